// Round 7
// baseline (739.605 us; speedup 1.0000x reference)
//
#include <hip/hip_runtime.h>

// RStarcoderAttention: MoE-LoRA QKV proj + RoPE + causal flash attention + LoRA out proj.
// B=2 S=2048 E=2048 H=16 D=128 NE=8 R=16. fp32 accumulation everywhere.
// Round 13: GEMM geometry fix. k_gemm3b: BM=128 x BN=256, BK=64, 8 waves (2m x 4n),
// THREE LDS buffers (144 KB) with stage-2-ahead and ONE counted s_waitcnt vmcnt(6)
// per K-step (never 0 mid-loop; stage(t+2) A@P0 / B@P1; provably drains stage(t+1)).
// Fragment-native granules (0 bank conflicts, r10-verified). QKV grid 24x32 = 768
// blocks = exactly 3 full rounds of 256 CUs (no half-idle round); out-proj 8x32 =
// 256 = one exact round with 16-MFMA phases. Flash6 (151us, r8) + split-K LoRA +
// cvt/rope/transpose unchanged. Numerics identical to r12 (absmax 0.3049316).

#define B_ 2
#define S_ 2048
#define E_ 2048
#define H_ 16
#define D_ 128
#define NE_ 8
#define R_ 16
#define HD_ 2048
#define M_ 4096          // B*S tokens
#define KL_ 128          // NE*R

typedef unsigned short u16;
typedef unsigned int u32;
typedef __attribute__((ext_vector_type(8))) short bf16x8;
typedef __attribute__((ext_vector_type(4))) float f32x4;

typedef const __attribute__((address_space(1))) void gvoid_t;
typedef __attribute__((address_space(3))) void svoid_t;

__device__ __forceinline__ float bf2f(u16 u) {
    union { u32 i; float f; } v; v.i = ((u32)u) << 16; return v.f;
}
__device__ __forceinline__ u16 f2bf(float f) {
    union { float f; u32 i; } v; v.f = f;
    u32 x = v.i;
    return (u16)((x + 0x7fffu + ((x >> 16) & 1u)) >> 16);   // RNE
}
__device__ __forceinline__ float ldf(const void* p, size_t i, int f) {
    return f ? ((const float*)p)[i] : bf2f(((const u16*)p)[i]);
}
__device__ __forceinline__ float4 ld4(const void* p, size_t i, int f) {
    if (f) return *(const float4*)((const float*)p + i);
    ushort4 v = *(const ushort4*)((const u16*)p + i);
    return make_float4(bf2f(v.x), bf2f(v.y), bf2f(v.z), bf2f(v.w));
}

// ---------------------------------------------------------------------------
__global__ void k_detect(const void* __restrict__ x, int* __restrict__ flags) {
    __shared__ int votes[2];
    int tid = threadIdx.x;
    if (tid < 2) votes[tid] = 0;
    __syncthreads();
    const u32* p = (const u32*)x;
    int bad = 0, tot = 0;
    for (int i = tid; i < 4096; i += 64) {
        u32 lo = p[i] & 0xffffu;
        if (lo) {
            tot++;
            int e = (int)((lo >> 7) & 0xffu);
            if (e < 100 || e > 150) bad++;
        }
    }
    atomicAdd(&votes[0], bad);
    atomicAdd(&votes[1], tot);
    __syncthreads();
    if (tid == 0) flags[0] = (votes[1] > 0 && votes[0] * 10 > votes[1] * 3) ? 1 : 0;
}

// ---------------------------------------------------------------------------
// Generic fp32/bf16 -> bf16 conversion (4 el/thread).
__global__ void k_cvt(const void* __restrict__ src, u16* __restrict__ dst, int n,
                      const int* __restrict__ flags) {
    int fin = flags[0];
    int i = (blockIdx.x * 256 + threadIdx.x) * 4;
    if (i >= n) return;
    float4 v = ld4(src, i, fin);
    ushort4 o;
    o.x = f2bf(v.x); o.y = f2bf(v.y); o.z = f2bf(v.z); o.w = f2bf(v.w);
    *(ushort4*)(dst + i) = o;
}

// f32 -> bf16 (4 el/thread), always-f32 source.
__global__ void k_cvtf(const float* __restrict__ src, u16* __restrict__ dst, int n) {
    int i = (blockIdx.x * 256 + threadIdx.x) * 4;
    if (i >= n) return;
    float4 v = *(const float4*)(src + i);
    ushort4 o;
    o.x = f2bf(v.x); o.y = f2bf(v.y); o.z = f2bf(v.z); o.w = f2bf(v.w);
    *(ushort4*)(dst + i) = o;
}

// zero f32 buffer (float4/thread)
__global__ void k_zero(float4* __restrict__ p, int n4) {
    int i = blockIdx.x * 256 + threadIdx.x;
    if (i < n4) p[i] = make_float4(0.f, 0.f, 0.f, 0.f);
}

// ---------------------------------------------------------------------------
// Batched conversion: x -> Xb; Aq..Ao -> Acat; Bq..Bo -> Bmcat; Wq/Wk/Wv -> Wcat.
#define NX_  8388608L   // M*E
#define NA1_ 262144L    // KL*E (also HD*KL)
#define NW_  4194304L   // E*HD
__global__ void k_cvt_all(
    const void* __restrict__ x,
    const void* __restrict__ Aq, const void* __restrict__ Ak,
    const void* __restrict__ Av, const void* __restrict__ Ao,
    const void* __restrict__ Bq, const void* __restrict__ Bk,
    const void* __restrict__ Bv, const void* __restrict__ Bo,
    const void* __restrict__ Wq, const void* __restrict__ Wk,
    const void* __restrict__ Wv,
    u16* __restrict__ Xb, u16* __restrict__ Acat, u16* __restrict__ Bmcat,
    u16* __restrict__ Wcat,
    const int* __restrict__ flags) {
    int fin = flags[0];
    long i = (long)(blockIdx.x * 256 + threadIdx.x) * 4;
    const void* src; u16* dst; long off;
    if (i < NX_) { src = x; dst = Xb; off = i; }
    else if (i < NX_ + 4 * NA1_) {
        long j = i - NX_; int p = (int)(j >> 18); off = j & (NA1_ - 1);
        src = (p == 0) ? Aq : (p == 1) ? Ak : (p == 2) ? Av : Ao;
        dst = Acat + (long)p * NA1_;
    } else if (i < NX_ + 8 * NA1_) {
        long j = i - NX_ - 4 * NA1_; int p = (int)(j >> 18); off = j & (NA1_ - 1);
        src = (p == 0) ? Bq : (p == 1) ? Bk : (p == 2) ? Bv : Bo;
        dst = Bmcat + (long)p * NA1_;
    } else {
        long j = i - NX_ - 8 * NA1_; int p = (int)(j / NW_); off = j - (long)p * NW_;
        src = (p == 0) ? Wq : (p == 1) ? Wk : Wv;
        dst = Wcat + (long)p * NW_;
    }
    float4 v = ld4(src, off, fin);
    ushort4 o;
    o.x = f2bf(v.x); o.y = f2bf(v.y); o.z = f2bf(v.z); o.w = f2bf(v.w);
    *(ushort4*)(dst + off) = o;
}

// ---------------------------------------------------------------------------
// Split-K GEMM for the small LoRA projections: Cf[m][n] += mask * sum_k A*B.
#define BM_ 128
#define BN_ 128
#define BK_ 64

__global__ __launch_bounds__(256, 2) void k_gemm_sk(
    const u16* __restrict__ A, int lda,
    const u16* __restrict__ Bw, int ldb, int K,
    const void* __restrict__ mask,
    float* __restrict__ Cf, int ldc,
    const int* __restrict__ flags) {
    __shared__ __align__(16) u16 As[BM_ * BK_];   // 16 KB
    __shared__ __align__(16) u16 Bs[BN_ * BK_];   // 16 KB
    int fin = flags[0];
    int tid = threadIdx.x;
    int w = tid >> 6, lane = tid & 63;
    int l15 = lane & 15, quad = lane >> 4;
    int wm = w >> 1, wn = w & 1;
    int m0 = blockIdx.y * BM_, n0 = blockIdx.x * BN_;
    int lrow = lane >> 3;          // 0..7
    int lcol = (lane & 7) * 8;     // 16B granule

    f32x4 acc[4][4];
#pragma unroll
    for (int mt = 0; mt < 4; mt++)
#pragma unroll
        for (int nt = 0; nt < 4; nt++)
#pragma unroll
            for (int r = 0; r < 4; r++) acc[mt][nt][r] = 0.f;

    int iters = (K / BK_) / gridDim.z;
    int it0 = blockIdx.z * iters;
    for (int it = it0; it < it0 + iters; it++) {
        int kb = it * BK_;
        __syncthreads();
#pragma unroll
        for (int i = 0; i < 4; i++) {
            int rowb = (w * 4 + i) * 8;
            int r = rowb + lrow;
            __builtin_amdgcn_global_load_lds(
                (gvoid_t*)(A + (size_t)(m0 + r) * lda + kb + lcol),
                (svoid_t*)(As + rowb * BK_), 16, 0, 0);
            __builtin_amdgcn_global_load_lds(
                (gvoid_t*)(Bw + (size_t)(n0 + r) * ldb + kb + lcol),
                (svoid_t*)(Bs + rowb * BK_), 16, 0, 0);
        }
        __syncthreads();
#pragma unroll
        for (int kk = 0; kk < 2; kk++) {
            int ko = kk * 32 + quad * 8;
            bf16x8 af[4], bf[4];
#pragma unroll
            for (int mt = 0; mt < 4; mt++)
                af[mt] = *(const bf16x8*)(As + (wm * 64 + mt * 16 + l15) * BK_ + ko);
#pragma unroll
            for (int nt = 0; nt < 4; nt++)
                bf[nt] = *(const bf16x8*)(Bs + (wn * 64 + nt * 16 + l15) * BK_ + ko);
#pragma unroll
            for (int mt = 0; mt < 4; mt++)
#pragma unroll
                for (int nt = 0; nt < 4; nt++)
                    acc[mt][nt] = __builtin_amdgcn_mfma_f32_16x16x32_bf16(
                        af[mt], bf[nt], acc[mt][nt], 0, 0, 0);
        }
    }

#pragma unroll
    for (int mt = 0; mt < 4; mt++) {
#pragma unroll
        for (int r = 0; r < 4; r++) {
            int m = m0 + wm * 64 + mt * 16 + quad * 4 + r;
#pragma unroll
            for (int nt = 0; nt < 4; nt++) {
                int n = n0 + wn * 64 + nt * 16 + l15;
                float v = acc[mt][nt][r] * ldf(mask, (size_t)m * NE_ + ((n & 127) >> 4), fin);
                atomicAdd(&Cf[(size_t)m * ldc + n], v);
            }
        }
    }
}

// ---------------------------------------------------------------------------
// Big GEMM: 128x256 tile, BK=64, 8 waves (2m x 4n), THREE LDS buffers (144 KB),
// stage 2 K-steps ahead (A(t+2)@P0, B(t+2)@P1), one counted s_waitcnt vmcnt(6)
// per K-step (drains stage(t+1), leaves stage(t+2)'s 6 loads in flight; never 0
// mid-loop). Fragment-native 16x32 granules (1 KB, lane-linear, conflict-free).
// Per K-step: P0 {af x8 + bf01 x4 reads | stage A(t+2) | bar;lgkm0 | 16 MFMA | bar}
//             P1 {bf23 x4 reads | stage B(t+2) | bar;lgkm0 | 16 MFMA | vmcnt(6) | bar}
// WAR-safe: buf (t+2)%3 was last read at step t-1, already barrier-closed.
// store_mode 2: C f32/bf16 by fin; store_mode 3: fused QKV (p = n0>>11 selects
// bias / lora segment / output third; BN=256 divides 2048 so p is block-uniform).
__global__ __launch_bounds__(512, 2) void k_gemm3b(
    const u16* __restrict__ A, int lda,
    const u16* __restrict__ Bw, int ldb, int K1,
    const u16* __restrict__ A2, int lda2,
    const u16* __restrict__ B2, int K2,
    const void* __restrict__ bias0, const void* __restrict__ bias1,
    const void* __restrict__ bias2,
    void* __restrict__ C, int ldc, int store_mode,
    const int* __restrict__ flags) {
    __shared__ __align__(16) u16 As[3][128 * 64];   // 3 x 16 KB
    __shared__ __align__(16) u16 Bs[3][256 * 64];   // 3 x 32 KB
    int fin = flags[0];
    int tid = threadIdx.x;
    int w = tid >> 6, lane = tid & 63;
    int l15 = lane & 15, quad = lane >> 4;
    int wm = w >> 2, wn = w & 3;             // 2m x 4n wave grid

    // XCD-aware swizzle (grid sizes are multiples of 8: 768, 256)
    int lin = blockIdx.y * gridDim.x + blockIdx.x;
    int cpx = (gridDim.x * gridDim.y) >> 3;
    int wg = (lin & 7) * cpx + (lin >> 3);
    int m0 = (wg / gridDim.x) * 128;
    int n0 = (wg % gridDim.x) * 256;

    int p = (store_mode == 3) ? (n0 >> 11) : 0;
    const u16* A2p = A2 + p * 128;
    const u16* B2p = B2 + (long)p * NA1_;
    int nloc = (store_mode == 3) ? (n0 & 2047) : n0;

    int nk1 = K1 >> 6;
    int NT = nk1 + (K2 >> 6);

    f32x4 acc[4][4];
#pragma unroll
    for (int mt = 0; mt < 4; mt++)
#pragma unroll
        for (int nt = 0; nt < 4; nt++)
#pragma unroll
            for (int r = 0; r < 4; r++) acc[mt][nt][r] = 0.f;

    // A tile 128x64 = 16 granules (rowsub 0..7 x khalf 0..1); wave w stages 2.
    auto stageA = [&](int s) {
        const u16* pa; size_t sa; int kc;
        if (s < nk1) { pa = A;   sa = (size_t)lda;  kc = s * 64; }
        else         { pa = A2p; sa = (size_t)lda2; kc = (s - nk1) * 64; }
        int buf = s % 3;
#pragma unroll
        for (int j = 0; j < 2; j++) {
            int g = w * 2 + j;
            __builtin_amdgcn_global_load_lds(
                (gvoid_t*)(pa + (size_t)(m0 + (g >> 1) * 16 + l15) * sa
                           + kc + (g & 1) * 32 + quad * 8),
                (svoid_t*)(&As[buf][g * 512]), 16, 0, 0);
        }
    };
    // B tile 256x64 = 32 granules; wave w stages 4.
    auto stageB = [&](int s) {
        const u16* pb; size_t sb; int kc, nb;
        if (s < nk1) { pb = Bw;  sb = (size_t)ldb; kc = s * 64;          nb = n0; }
        else         { pb = B2p; sb = (size_t)K2;  kc = (s - nk1) * 64;  nb = nloc; }
        int buf = s % 3;
#pragma unroll
        for (int j = 0; j < 4; j++) {
            int g = w * 4 + j;
            __builtin_amdgcn_global_load_lds(
                (gvoid_t*)(pb + (size_t)(nb + (g >> 1) * 16 + l15) * sb
                           + kc + (g & 1) * 32 + quad * 8),
                (svoid_t*)(&Bs[buf][g * 512]), 16, 0, 0);
        }
    };

    // prologue: stage(0), stage(1) fully; drain stage(0) (leave stage(1)'s 6)
    stageA(0); stageB(0);
    if (NT > 1) { stageA(1); stageB(1); }
    if (NT > 1) asm volatile("s_waitcnt vmcnt(6)" ::: "memory");
    else        asm volatile("s_waitcnt vmcnt(0)" ::: "memory");
    __builtin_amdgcn_s_barrier();

    for (int t = 0; t < NT; t++) {
        int buf = t % 3;
        bf16x8 af[4][2], bf[4][2];

        // ---- P0: af x8 + bf01 x4 reads; stage A(t+2)
#pragma unroll
        for (int mt = 0; mt < 4; mt++)
#pragma unroll
            for (int kh = 0; kh < 2; kh++)
                af[mt][kh] = *(const bf16x8*)(&As[buf][((wm * 4 + mt) * 2 + kh) * 512 + lane * 8]);
#pragma unroll
        for (int nt = 0; nt < 2; nt++)
#pragma unroll
            for (int kh = 0; kh < 2; kh++)
                bf[nt][kh] = *(const bf16x8*)(&Bs[buf][((wn * 4 + nt) * 2 + kh) * 512 + lane * 8]);
        if (t + 2 < NT) stageA(t + 2);
        __builtin_amdgcn_s_barrier();
        asm volatile("s_waitcnt lgkmcnt(0)" ::: "memory");
        __builtin_amdgcn_sched_barrier(0);
        __builtin_amdgcn_s_setprio(1);
#pragma unroll
        for (int mt = 0; mt < 4; mt++)
#pragma unroll
            for (int nt = 0; nt < 2; nt++) {
                acc[mt][nt] = __builtin_amdgcn_mfma_f32_16x16x32_bf16(af[mt][0], bf[nt][0], acc[mt][nt], 0, 0, 0);
                acc[mt][nt] = __builtin_amdgcn_mfma_f32_16x16x32_bf16(af[mt][1], bf[nt][1], acc[mt][nt], 0, 0, 0);
            }
        __builtin_amdgcn_s_setprio(0);
        __builtin_amdgcn_s_barrier();

        // ---- P1: bf23 x4 reads; stage B(t+2); counted vmcnt
#pragma unroll
        for (int nt = 2; nt < 4; nt++)
#pragma unroll
            for (int kh = 0; kh < 2; kh++)
                bf[nt][kh] = *(const bf16x8*)(&Bs[buf][((wn * 4 + nt) * 2 + kh) * 512 + lane * 8]);
        if (t + 2 < NT) stageB(t + 2);
        __builtin_amdgcn_s_barrier();
        asm volatile("s_waitcnt lgkmcnt(0)" ::: "memory");
        __builtin_amdgcn_sched_barrier(0);
        __builtin_amdgcn_s_setprio(1);
#pragma unroll
        for (int mt = 0; mt < 4; mt++)
#pragma unroll
            for (int nt = 2; nt < 4; nt++) {
                acc[mt][nt] = __builtin_amdgcn_mfma_f32_16x16x32_bf16(af[mt][0], bf[nt][0], acc[mt][nt], 0, 0, 0);
                acc[mt][nt] = __builtin_amdgcn_mfma_f32_16x16x32_bf16(af[mt][1], bf[nt][1], acc[mt][nt], 0, 0, 0);
            }
        __builtin_amdgcn_s_setprio(0);
        if (t + 2 < NT)      asm volatile("s_waitcnt vmcnt(6)" ::: "memory");
        else if (t + 1 < NT) asm volatile("s_waitcnt vmcnt(0)" ::: "memory");
        __builtin_amdgcn_s_barrier();
    }

    const void* bp = (store_mode == 3) ? (p == 0 ? bias0 : p == 1 ? bias1 : bias2)
                                       : bias0;
#pragma unroll
    for (int mt = 0; mt < 4; mt++) {
#pragma unroll
        for (int r = 0; r < 4; r++) {
            int m = m0 + wm * 64 + mt * 16 + quad * 4 + r;
#pragma unroll
            for (int nt = 0; nt < 4; nt++) {
                int n = n0 + wn * 64 + nt * 16 + l15;
                float v = acc[mt][nt][r];
                if (bp) v += ldf(bp, (size_t)(n & 2047), fin);
                if (store_mode == 3) {
                    ((u16*)C)[(size_t)p * 8388608 + (size_t)m * 2048 + (n & 2047)] = f2bf(v);
                } else {
                    if (fin) ((float*)C)[(size_t)m * ldc + n] = v;
                    else     ((u16*)C)[(size_t)m * ldc + n] = f2bf(v);
                }
            }
        }
    }
}

// ---------------------------------------------------------------------------
// RoPE in place on Q and K in one launch.
__global__ void k_rope2(u16* __restrict__ Q, u16* __restrict__ K) {
    const int n = M_ * HD_ / 2;
    int idx = blockIdx.x * 256 + threadIdx.x;
    u16* Y = (idx < n) ? Q : K;
    int id = (idx < n) ? idx : idx - n;
    int d2 = id & 63;
    int sh = id >> 6;
    int s = (sh >> 4) & (S_ - 1);
    float inv = powf(10000.f, -(float)d2 * (1.f / 64.f));
    float fr = (float)s * inv;
    float c, sn;
    sincosf(fr, &sn, &c);
    size_t base = ((size_t)sh) << 7;
    float t0 = bf2f(Y[base + d2]);
    float t1 = bf2f(Y[base + d2 + 64]);
    Y[base + d2]      = f2bf(t0 * c - t1 * sn);
    Y[base + d2 + 64] = f2bf(t1 * c + t0 * sn);
}

// ---------------------------------------------------------------------------
// Vb [B,S,H*D] -> Vt [B*H*D, S]
__global__ void k_transpose_v(const u16* __restrict__ Vb, u16* __restrict__ Vt) {
    __shared__ u16 t[32][33];
    int s0 = blockIdx.x * 32;
    int n0 = blockIdx.y * 32;
    int b  = blockIdx.z;
    int tx = threadIdx.x & 31, ty = threadIdx.x >> 5;
#pragma unroll
    for (int r = 0; r < 4; r++)
        t[ty + r * 8][tx] = Vb[((size_t)(b * S_ + s0 + ty + r * 8)) * HD_ + n0 + tx];
    __syncthreads();
#pragma unroll
    for (int r = 0; r < 4; r++)
        Vt[((size_t)(b * HD_ + n0 + ty + r * 8)) * S_ + s0 + tx] = t[tx][ty + r * 8];
}

// ---------------------------------------------------------------------------
// MFMA flash attention (r8): 64-query tiles, LDS-staged K/V, swapped QK^T
// softmax (lane-local row, 4 shuffles/chunk). Unchanged.
#define KS_ST 136
#define VT_ST 72
#define SCALE_ 0.088388347648318447f

__global__ __launch_bounds__(256, 3) void k_flash6(
    const u16* __restrict__ Q, const u16* __restrict__ K,
    const u16* __restrict__ Vt, u16* __restrict__ O) {
    __shared__ __align__(16) u16 Ks[64 * KS_ST];    // 17408 B
    __shared__ __align__(16) u16 Vs[128 * VT_ST];   // 18432 B
    __shared__ __align__(16) u16 Ps[64 * VT_ST];    //  9216 B
    int tid = threadIdx.x;
    int w = tid >> 6, lane = tid & 63;
    int l15 = lane & 15, quad = lane >> 4;
    int bh = blockIdx.y, b = bh >> 4, h = bh & 15;
    int t = 31 - blockIdx.x;                 // heavy tiles dispatched first
    int q0 = t * 64;

    int krow[4], kd8[4], vd[4], vkg[4];
#pragma unroll
    for (int it = 0; it < 4; it++) {
        int idx = it * 256 + tid;
        krow[it] = idx >> 4; kd8[it] = (idx & 15) * 8;
        vd[it] = idx >> 3;   vkg[it] = (idx & 7) * 8;
    }

    bf16x8 qf[4];
    size_t baseQ = ((size_t)(b * S_ + q0 + w * 16 + l15)) * HD_ + h * D_;
#pragma unroll
    for (int ks = 0; ks < 4; ks++)
        qf[ks] = *(const bf16x8*)(Q + baseQ + ks * 32 + quad * 8);

    f32x4 of[8];
#pragma unroll
    for (int nt = 0; nt < 8; nt++)
#pragma unroll
        for (int r = 0; r < 4; r++) of[nt][r] = 0.f;
    float mreg = -30000.f, lreg = 0.f;
    int qrow = q0 + w * 16 + l15;

    int nch = t + 1;

    bf16x8 kpre[4], vpre[4];
#pragma unroll
    for (int it = 0; it < 4; it++) {
        kpre[it] = *(const bf16x8*)(K + ((size_t)(b * S_ + krow[it])) * HD_ + h * D_ + kd8[it]);
        vpre[it] = *(const bf16x8*)(Vt + ((size_t)(bh * 128 + vd[it])) * S_ + vkg[it]);
    }

    for (int c = 0; c < nch; c++) {
        int k0 = c * 64;
        __syncthreads();
#pragma unroll
        for (int it = 0; it < 4; it++) {
            *(bf16x8*)(Ks + krow[it] * KS_ST + kd8[it]) = kpre[it];
            *(bf16x8*)(Vs + vd[it] * VT_ST + vkg[it]) = vpre[it];
        }
        __syncthreads();
        if (c + 1 < nch) {
            int k1 = k0 + 64;
#pragma unroll
            for (int it = 0; it < 4; it++) {
                kpre[it] = *(const bf16x8*)(K + ((size_t)(b * S_ + k1 + krow[it])) * HD_ + h * D_ + kd8[it]);
                vpre[it] = *(const bf16x8*)(Vt + ((size_t)(bh * 128 + vd[it])) * S_ + k1 + vkg[it]);
            }
        }

        f32x4 sf[4];
#pragma unroll
        for (int nt = 0; nt < 4; nt++)
#pragma unroll
            for (int r = 0; r < 4; r++) sf[nt][r] = 0.f;
#pragma unroll
        for (int ks = 0; ks < 4; ks++) {
            int koff = ks * 32 + quad * 8;
            bf16x8 qa = qf[ks];
#pragma unroll
            for (int nt = 0; nt < 4; nt++) {
                bf16x8 kb = *(const bf16x8*)(Ks + (nt * 16 + l15) * KS_ST + koff);
                sf[nt] = __builtin_amdgcn_mfma_f32_16x16x32_bf16(kb, qa, sf[nt], 0, 0, 0);
            }
        }

#pragma unroll
        for (int nt = 0; nt < 4; nt++) {
            int keyb = k0 + nt * 16 + quad * 4;
#pragma unroll
            for (int r = 0; r < 4; r++) {
                float sv = sf[nt][r] * SCALE_;
                sf[nt][r] = (keyb + r > qrow) ? -30000.f : sv;
            }
        }

        float t0 = fmaxf(fmaxf(sf[0][0], sf[0][1]), fmaxf(sf[0][2], sf[0][3]));
        float t1 = fmaxf(fmaxf(sf[1][0], sf[1][1]), fmaxf(sf[1][2], sf[1][3]));
        float t2 = fmaxf(fmaxf(sf[2][0], sf[2][1]), fmaxf(sf[2][2], sf[2][3]));
        float t3 = fmaxf(fmaxf(sf[3][0], sf[3][1]), fmaxf(sf[3][2], sf[3][3]));
        float cmax = fmaxf(fmaxf(t0, t1), fmaxf(t2, t3));
        cmax = fmaxf(cmax, __shfl_xor(cmax, 16, 64));
        cmax = fmaxf(cmax, __shfl_xor(cmax, 32, 64));
        float mnew = fmaxf(mreg, cmax);
        float a = __expf(mreg - mnew);
        mreg = mnew;
#pragma unroll
        for (int nt = 0; nt < 4; nt++)
#pragma unroll
            for (int r = 0; r < 4; r++)
                sf[nt][r] = __expf(sf[nt][r] - mnew);
        float s0 = (sf[0][0] + sf[0][1]) + (sf[0][2] + sf[0][3]);
        float s1 = (sf[1][0] + sf[1][1]) + (sf[1][2] + sf[1][3]);
        float s2 = (sf[2][0] + sf[2][1]) + (sf[2][2] + sf[2][3]);
        float s3 = (sf[3][0] + sf[3][1]) + (sf[3][2] + sf[3][3]);
        float psum = (s0 + s1) + (s2 + s3);
        psum += __shfl_xor(psum, 16, 64);
        psum += __shfl_xor(psum, 32, 64);
        lreg = lreg * a + psum;

        float al[4];
#pragma unroll
        for (int r = 0; r < 4; r++) al[r] = __shfl(a, quad * 4 + r, 16);

#pragma unroll
        for (int nt = 0; nt < 4; nt++)
#pragma unroll
            for (int r = 0; r < 4; r++)
                Ps[(w * 16 + l15) * VT_ST + nt * 16 + quad * 4 + r] = f2bf(sf[nt][r]);
#pragma unroll
        for (int nt = 0; nt < 8; nt++)
#pragma unroll
            for (int r = 0; r < 4; r++) of[nt][r] *= al[r];

#pragma unroll
        for (int ks2 = 0; ks2 < 2; ks2++) {
            int koff = ks2 * 32 + quad * 8;
            bf16x8 pa = *(const bf16x8*)(Ps + (w * 16 + l15) * VT_ST + koff);
#pragma unroll
            for (int nt = 0; nt < 8; nt++) {
                bf16x8 vb = *(const bf16x8*)(Vs + (nt * 16 + l15) * VT_ST + koff);
                of[nt] = __builtin_amdgcn_mfma_f32_16x16x32_bf16(pa, vb, of[nt], 0, 0, 0);
            }
        }
    }

    float linv = 1.f / lreg;
    float inv[4];
#pragma unroll
    for (int r = 0; r < 4; r++) inv[r] = __shfl(linv, quad * 4 + r, 16);
    int rowb = q0 + w * 16 + quad * 4;
#pragma unroll
    for (int r = 0; r < 4; r++) {
        size_t base = ((size_t)(b * S_ + rowb + r)) * HD_ + h * D_;
#pragma unroll
        for (int nt = 0; nt < 8; nt++)
            O[base + nt * 16 + l15] = f2bf(of[nt][r] * inv[r]);
    }
}

// ---------------------------------------------------------------------------
extern "C" void kernel_launch(void* const* d_in, const int* in_sizes, int n_in,
                              void* d_out, int out_size, void* d_ws, size_t ws_size,
                              hipStream_t stream) {
    const void* x    = d_in[0];
    const void* mask = d_in[1];
    const void* Wq = d_in[2];  const void* bq = d_in[3];
    const void* Aq = d_in[4];  const void* Bq = d_in[5];
    const void* Wk = d_in[6];  const void* bk = d_in[7];
    const void* Ak = d_in[8];  const void* Bk = d_in[9];
    const void* Wv = d_in[10]; const void* bv = d_in[11];
    const void* Av = d_in[12]; const void* Bv = d_in[13];
    const void* Wo = d_in[14]; const void* bo = d_in[15];
    const void* Ao = d_in[16]; const void* Bo = d_in[17];

    char* ws = (char*)d_ws;
    const long MB = 1 << 20;
    int* flags = (int*)ws;
    u16* Xb    = (u16*)(ws + 1  * MB);   // 16 MB
    u16* Acat  = (u16*)(ws + 17 * MB);   // 2 MB
    u16* Bmcat = (u16*)(ws + 19 * MB);   // 2 MB
    u16* hg3   = (u16*)(ws + 21 * MB);   // 3 MB  [M,384] bf16
    u16* hgo   = (u16*)(ws + 24 * MB);   // 1 MB  [M,128] bf16
    u16* Qb    = (u16*)(ws + 25 * MB);   // 16 MB; hg3f pre-lives here; Wob after flash
    u16* Kb    = (u16*)(ws + 41 * MB);   // 16 MB; hgof after flash
    u16* Vb    = (u16*)(ws + 57 * MB);   // 16 MB; Ob after transpose
    u16* Vt    = (u16*)(ws + 73 * MB);   // 16 MB (written after Wcat dead)
    u16* Wcat  = (u16*)(ws + 73 * MB);   // 24 MB [6144][2048]; dead after QKV GEMM (end 97 MB)
    float* hg3f = (float*)Qb;            // 6 MB  [M,384] f32 (dead before QKV writes Qb)
    float* hgof = (float*)Kb;            // 2 MB  [M,128] f32 (Kb dead after flash)
    u16* Wob   = Qb;                     // Wo converted after flash (Qb dead)
    u16* Ob    = Vb;                     // Vb dead after transpose

    k_detect<<<1, 64, 0, stream>>>(x, flags);
    k_zero<<<1536, 256, 0, stream>>>((float4*)hg3f, 393216);     // 4096*384 f32
    const long NCVT = NX_ + 8 * NA1_ + 3 * NW_;   // 23068672
    k_cvt_all<<<NCVT / 1024, 256, 0, stream>>>(
        x, Aq, Ak, Av, Ao, Bq, Bk, Bv, Bo, Wq, Wk, Wv,
        Xb, Acat, Bmcat, Wcat, flags);

    // qkv LoRA-h: hg3f[m][p*128+er] via split-K x4, then cvt to bf16
    k_gemm_sk<<<dim3(3, M_ / BM_, 4), 256, 0, stream>>>(
        Xb, E_, Acat, E_, E_, mask, hg3f, 384, flags);
    k_cvtf<<<1536, 256, 0, stream>>>(hg3f, hg3, 1572864);

    // fused QKV projection: 128x256 tiles, grid 24x32 = 768 = 3 exact rounds
    k_gemm3b<<<dim3(6144 / 256, M_ / 128), 512, 0, stream>>>(
        Xb, E_, Wcat, E_, E_, hg3, 384, Bmcat, KL_,
        bq, bk, bv, Qb, HD_, 3, flags);

    k_rope2<<<(M_ * HD_) / 256, 256, 0, stream>>>(Qb, Kb);
    k_transpose_v<<<dim3(S_ / 32, HD_ / 32, B_), 256, 0, stream>>>(Vb, Vt);

    k_flash6<<<dim3(32, 32), 256, 0, stream>>>(Qb, Kb, Vt, Ob);

    // out-proj LoRA-h via split-K x4 (into dead Kb region), Wo cvt (dead Qb region)
    k_zero<<<512, 256, 0, stream>>>((float4*)hgof, 131072);      // 4096*128 f32
    k_cvt<<<NW_ / 1024, 256, 0, stream>>>(Wo, Wob, (int)NW_, flags);
    k_gemm_sk<<<dim3(1, M_ / BM_, 4), 256, 0, stream>>>(
        Ob, HD_, Acat + 3 * NA1_, E_, E_, mask, hgof, KL_, flags);
    k_cvtf<<<512, 256, 0, stream>>>(hgof, hgo, 524288);

    // output projection: 128x256 tiles, grid 8x32 = 256 = one exact round
    k_gemm3b<<<dim3(HD_ / 256, M_ / 128), 512, 0, stream>>>(
        Ob, HD_, Wob, E_, E_, hgo, KL_, Bmcat + 3 * NA1_, KL_,
        bo, nullptr, nullptr, d_out, HD_, 2, flags);
}

// Round 8
// 720.912 us; speedup vs baseline: 1.0259x; 1.0259x over previous
//
#include <hip/hip_runtime.h>

// RStarcoderAttention: MoE-LoRA QKV proj + RoPE + causal flash attention + LoRA out proj.
// B=2 S=2048 E=2048 H=16 D=128 NE=8 R=16. fp32 accumulation everywhere.
// Round 14: reallocation round.
//  * Big GEMM: reverted to r11's k_gemm8p (best measured: QKV 210us) — 4 LDS bufs,
//    BK=32, 3-tile prefetch, counted vmcnt(8/6). Schedule exploration closed (5 rounds,
//    210-261us plateau; not BW-bound, not MFMA-bound; lockstep cost accepted).
//  * Flash7: K/V reg-prefetch depth 2 (even/odd sets, ~144 VGPR, 12 waves/CU kept) +
//    XCD-contiguous swizzle (4 bh per XCD -> K/V L2-resident, FETCH 125->~65MB).
//  * k_rope3: 1 thread = (b,s,4xd2) covers all 16 heads -> 64x fewer transcendentals,
//    ushort4 vectorized. Bit-identical math.
//  * Split-K LoRA GEMMs, cvt, transpose unchanged.

#define B_ 2
#define S_ 2048
#define E_ 2048
#define H_ 16
#define D_ 128
#define NE_ 8
#define R_ 16
#define HD_ 2048
#define M_ 4096          // B*S tokens
#define KL_ 128          // NE*R

typedef unsigned short u16;
typedef unsigned int u32;
typedef __attribute__((ext_vector_type(8))) short bf16x8;
typedef __attribute__((ext_vector_type(4))) float f32x4;

typedef const __attribute__((address_space(1))) void gvoid_t;
typedef __attribute__((address_space(3))) void svoid_t;

__device__ __forceinline__ float bf2f(u16 u) {
    union { u32 i; float f; } v; v.i = ((u32)u) << 16; return v.f;
}
__device__ __forceinline__ u16 f2bf(float f) {
    union { float f; u32 i; } v; v.f = f;
    u32 x = v.i;
    return (u16)((x + 0x7fffu + ((x >> 16) & 1u)) >> 16);   // RNE
}
__device__ __forceinline__ float ldf(const void* p, size_t i, int f) {
    return f ? ((const float*)p)[i] : bf2f(((const u16*)p)[i]);
}
__device__ __forceinline__ float4 ld4(const void* p, size_t i, int f) {
    if (f) return *(const float4*)((const float*)p + i);
    ushort4 v = *(const ushort4*)((const u16*)p + i);
    return make_float4(bf2f(v.x), bf2f(v.y), bf2f(v.z), bf2f(v.w));
}

// ---------------------------------------------------------------------------
__global__ void k_detect(const void* __restrict__ x, int* __restrict__ flags) {
    __shared__ int votes[2];
    int tid = threadIdx.x;
    if (tid < 2) votes[tid] = 0;
    __syncthreads();
    const u32* p = (const u32*)x;
    int bad = 0, tot = 0;
    for (int i = tid; i < 4096; i += 64) {
        u32 lo = p[i] & 0xffffu;
        if (lo) {
            tot++;
            int e = (int)((lo >> 7) & 0xffu);
            if (e < 100 || e > 150) bad++;
        }
    }
    atomicAdd(&votes[0], bad);
    atomicAdd(&votes[1], tot);
    __syncthreads();
    if (tid == 0) flags[0] = (votes[1] > 0 && votes[0] * 10 > votes[1] * 3) ? 1 : 0;
}

// ---------------------------------------------------------------------------
// Generic fp32/bf16 -> bf16 conversion (4 el/thread).
__global__ void k_cvt(const void* __restrict__ src, u16* __restrict__ dst, int n,
                      const int* __restrict__ flags) {
    int fin = flags[0];
    int i = (blockIdx.x * 256 + threadIdx.x) * 4;
    if (i >= n) return;
    float4 v = ld4(src, i, fin);
    ushort4 o;
    o.x = f2bf(v.x); o.y = f2bf(v.y); o.z = f2bf(v.z); o.w = f2bf(v.w);
    *(ushort4*)(dst + i) = o;
}

// f32 -> bf16 (4 el/thread), always-f32 source.
__global__ void k_cvtf(const float* __restrict__ src, u16* __restrict__ dst, int n) {
    int i = (blockIdx.x * 256 + threadIdx.x) * 4;
    if (i >= n) return;
    float4 v = *(const float4*)(src + i);
    ushort4 o;
    o.x = f2bf(v.x); o.y = f2bf(v.y); o.z = f2bf(v.z); o.w = f2bf(v.w);
    *(ushort4*)(dst + i) = o;
}

// zero f32 buffer (float4/thread)
__global__ void k_zero(float4* __restrict__ p, int n4) {
    int i = blockIdx.x * 256 + threadIdx.x;
    if (i < n4) p[i] = make_float4(0.f, 0.f, 0.f, 0.f);
}

// ---------------------------------------------------------------------------
// Batched conversion: x -> Xb; Aq..Ao -> Acat; Bq..Bo -> Bmcat; Wq/Wk/Wv -> Wcat.
#define NX_  8388608L   // M*E
#define NA1_ 262144L    // KL*E (also HD*KL)
#define NW_  4194304L   // E*HD
__global__ void k_cvt_all(
    const void* __restrict__ x,
    const void* __restrict__ Aq, const void* __restrict__ Ak,
    const void* __restrict__ Av, const void* __restrict__ Ao,
    const void* __restrict__ Bq, const void* __restrict__ Bk,
    const void* __restrict__ Bv, const void* __restrict__ Bo,
    const void* __restrict__ Wq, const void* __restrict__ Wk,
    const void* __restrict__ Wv,
    u16* __restrict__ Xb, u16* __restrict__ Acat, u16* __restrict__ Bmcat,
    u16* __restrict__ Wcat,
    const int* __restrict__ flags) {
    int fin = flags[0];
    long i = (long)(blockIdx.x * 256 + threadIdx.x) * 4;
    const void* src; u16* dst; long off;
    if (i < NX_) { src = x; dst = Xb; off = i; }
    else if (i < NX_ + 4 * NA1_) {
        long j = i - NX_; int p = (int)(j >> 18); off = j & (NA1_ - 1);
        src = (p == 0) ? Aq : (p == 1) ? Ak : (p == 2) ? Av : Ao;
        dst = Acat + (long)p * NA1_;
    } else if (i < NX_ + 8 * NA1_) {
        long j = i - NX_ - 4 * NA1_; int p = (int)(j >> 18); off = j & (NA1_ - 1);
        src = (p == 0) ? Bq : (p == 1) ? Bk : (p == 2) ? Bv : Bo;
        dst = Bmcat + (long)p * NA1_;
    } else {
        long j = i - NX_ - 8 * NA1_; int p = (int)(j / NW_); off = j - (long)p * NW_;
        src = (p == 0) ? Wq : (p == 1) ? Wk : Wv;
        dst = Wcat + (long)p * NW_;
    }
    float4 v = ld4(src, off, fin);
    ushort4 o;
    o.x = f2bf(v.x); o.y = f2bf(v.y); o.z = f2bf(v.z); o.w = f2bf(v.w);
    *(ushort4*)(dst + off) = o;
}

// ---------------------------------------------------------------------------
// Split-K GEMM for the small LoRA projections: Cf[m][n] += mask * sum_k A*B.
#define BM_ 128
#define BN_ 128
#define BK_ 64

__global__ __launch_bounds__(256, 2) void k_gemm_sk(
    const u16* __restrict__ A, int lda,
    const u16* __restrict__ Bw, int ldb, int K,
    const void* __restrict__ mask,
    float* __restrict__ Cf, int ldc,
    const int* __restrict__ flags) {
    __shared__ __align__(16) u16 As[BM_ * BK_];   // 16 KB
    __shared__ __align__(16) u16 Bs[BN_ * BK_];   // 16 KB
    int fin = flags[0];
    int tid = threadIdx.x;
    int w = tid >> 6, lane = tid & 63;
    int l15 = lane & 15, quad = lane >> 4;
    int wm = w >> 1, wn = w & 1;
    int m0 = blockIdx.y * BM_, n0 = blockIdx.x * BN_;
    int lrow = lane >> 3;          // 0..7
    int lcol = (lane & 7) * 8;     // 16B granule

    f32x4 acc[4][4];
#pragma unroll
    for (int mt = 0; mt < 4; mt++)
#pragma unroll
        for (int nt = 0; nt < 4; nt++)
#pragma unroll
            for (int r = 0; r < 4; r++) acc[mt][nt][r] = 0.f;

    int iters = (K / BK_) / gridDim.z;
    int it0 = blockIdx.z * iters;
    for (int it = it0; it < it0 + iters; it++) {
        int kb = it * BK_;
        __syncthreads();
#pragma unroll
        for (int i = 0; i < 4; i++) {
            int rowb = (w * 4 + i) * 8;
            int r = rowb + lrow;
            __builtin_amdgcn_global_load_lds(
                (gvoid_t*)(A + (size_t)(m0 + r) * lda + kb + lcol),
                (svoid_t*)(As + rowb * BK_), 16, 0, 0);
            __builtin_amdgcn_global_load_lds(
                (gvoid_t*)(Bw + (size_t)(n0 + r) * ldb + kb + lcol),
                (svoid_t*)(Bs + rowb * BK_), 16, 0, 0);
        }
        __syncthreads();
#pragma unroll
        for (int kk = 0; kk < 2; kk++) {
            int ko = kk * 32 + quad * 8;
            bf16x8 af[4], bf[4];
#pragma unroll
            for (int mt = 0; mt < 4; mt++)
                af[mt] = *(const bf16x8*)(As + (wm * 64 + mt * 16 + l15) * BK_ + ko);
#pragma unroll
            for (int nt = 0; nt < 4; nt++)
                bf[nt] = *(const bf16x8*)(Bs + (wn * 64 + nt * 16 + l15) * BK_ + ko);
#pragma unroll
            for (int mt = 0; mt < 4; mt++)
#pragma unroll
                for (int nt = 0; nt < 4; nt++)
                    acc[mt][nt] = __builtin_amdgcn_mfma_f32_16x16x32_bf16(
                        af[mt], bf[nt], acc[mt][nt], 0, 0, 0);
        }
    }

#pragma unroll
    for (int mt = 0; mt < 4; mt++) {
#pragma unroll
        for (int r = 0; r < 4; r++) {
            int m = m0 + wm * 64 + mt * 16 + quad * 4 + r;
#pragma unroll
            for (int nt = 0; nt < 4; nt++) {
                int n = n0 + wn * 64 + nt * 16 + l15;
                float v = acc[mt][nt][r] * ldf(mask, (size_t)m * NE_ + ((n & 127) >> 4), fin);
                atomicAdd(&Cf[(size_t)m * ldc + n], v);
            }
        }
    }
}

// ---------------------------------------------------------------------------
// Big GEMM (r11, best measured). Tile BMt x 256, BK=32, 8 waves (2m x 4n), 4 LDS
// buffers, 3-tile-deep prefetch, counted vmcnt once per K-tile. LDS subtiles
// fragment-native (16 rows x 32 k, lane-linear -> conflict-free ds_read_b128).
// store_mode 2: C f32/bf16 by fin; store_mode 3: fused QKV (p = n0>>11 selects
// bias / lora segment / output third).
template <int BMt>
__global__ __launch_bounds__(512, 2) void k_gemm8p(
    const u16* __restrict__ A, int lda,
    const u16* __restrict__ Bw, int ldb, int K1,
    const u16* __restrict__ A2, int lda2,
    const u16* __restrict__ B2, int K2,
    const void* __restrict__ bias0, const void* __restrict__ bias1,
    const void* __restrict__ bias2,
    void* __restrict__ C, int ldc, int store_mode,
    const int* __restrict__ flags) {
    constexpr int MT  = BMt / 32;    // m-frags per wave
    constexpr int NSA = BMt / 16;    // A subtiles per K-tile
    constexpr int LA  = BMt / 128;   // A stage loads per wave per tile
    constexpr int L   = LA + 2;      // total stage loads per wave per tile
    __shared__ __align__(16) u16 As[4][NSA * 512];   // 4 x (BMt*32) el
    __shared__ __align__(16) u16 Bs[4][16 * 512];    // 4 x 16 KB
    int fin = flags[0];
    int tid = threadIdx.x;
    int w = tid >> 6, lane = tid & 63;
    int l15 = lane & 15, quad = lane >> 4;
    int wm = w >> 2, wn = w & 3;             // 2 x 4 wave grid

    // XCD-aware swizzle (grid sizes are multiples of 8)
    int lin = blockIdx.y * gridDim.x + blockIdx.x;
    int cpx = (gridDim.x * gridDim.y) >> 3;
    int wg = (lin & 7) * cpx + (lin >> 3);
    int m0 = (wg / gridDim.x) * BMt;
    int n0 = (wg % gridDim.x) * 256;

    int p = (store_mode == 3) ? (n0 >> 11) : 0;
    const u16* A2p = A2 + p * 128;
    const u16* B2p = B2 + (long)p * NA1_;
    int nloc = (store_mode == 3) ? (n0 & 2047) : n0;

    int nk1 = K1 >> 5;
    int NT = nk1 + (K2 >> 5);

    f32x4 acc[MT][4];
#pragma unroll
    for (int mt = 0; mt < MT; mt++)
#pragma unroll
        for (int nt = 0; nt < 4; nt++)
#pragma unroll
            for (int r = 0; r < 4; r++) acc[mt][nt][r] = 0.f;

    auto stageA = [&](int kt) {
        const u16* pa; size_t sa; int kb;
        if (kt < nk1) { pa = A;   sa = (size_t)lda;  kb = kt * 32; }
        else          { pa = A2p; sa = (size_t)lda2; kb = (kt - nk1) * 32; }
        int buf = kt & 3;
#pragma unroll
        for (int j = 0; j < LA; j++) {
            int rb = w * LA + j;
            __builtin_amdgcn_global_load_lds(
                (gvoid_t*)(pa + (size_t)(m0 + rb * 16 + l15) * sa + kb + quad * 8),
                (svoid_t*)(&As[buf][rb * 512]), 16, 0, 0);
        }
    };
    auto stageB = [&](int kt) {
        const u16* pb; size_t sb; int kb, nb;
        if (kt < nk1) { pb = Bw;  sb = (size_t)ldb; kb = kt * 32;          nb = n0; }
        else          { pb = B2p; sb = (size_t)K2;  kb = (kt - nk1) * 32;  nb = nloc; }
        int buf = kt & 3;
#pragma unroll
        for (int j = 0; j < 2; j++) {
            int rb = w * 2 + j;
            __builtin_amdgcn_global_load_lds(
                (gvoid_t*)(pb + (size_t)(nb + rb * 16 + l15) * sb + kb + quad * 8),
                (svoid_t*)(&Bs[buf][rb * 512]), 16, 0, 0);
        }
    };

    // prologue: tiles 0,1,2 fully staged (3L loads in flight), wait tile 0
    stageA(0); stageB(0);
    stageA(1); stageB(1);
    stageA(2); stageB(2);
    if constexpr (L == 4) asm volatile("s_waitcnt vmcnt(8)" ::: "memory");
    else                  asm volatile("s_waitcnt vmcnt(6)" ::: "memory");
    __builtin_amdgcn_s_barrier();

    for (int kt = 0; kt < NT; kt++) {
        int buf = kt & 3;
        bool pre = (kt + 3 < NT);

        // ---- phase 0: read af (held through both phases) + bf01; stage A(kt+3)
        bf16x8 af[MT], bfr[4];
#pragma unroll
        for (int mt = 0; mt < MT; mt++)
            af[mt] = *(const bf16x8*)(&As[buf][(wm * MT + mt) * 512 + lane * 8]);
        bfr[0] = *(const bf16x8*)(&Bs[buf][(wn * 4 + 0) * 512 + lane * 8]);
        bfr[1] = *(const bf16x8*)(&Bs[buf][(wn * 4 + 1) * 512 + lane * 8]);
        if (pre) stageA(kt + 3);
        __builtin_amdgcn_s_barrier();
        asm volatile("s_waitcnt lgkmcnt(0)" ::: "memory");
        __builtin_amdgcn_sched_barrier(0);
        __builtin_amdgcn_s_setprio(1);
#pragma unroll
        for (int mt = 0; mt < MT; mt++) {
            acc[mt][0] = __builtin_amdgcn_mfma_f32_16x16x32_bf16(af[mt], bfr[0], acc[mt][0], 0, 0, 0);
            acc[mt][1] = __builtin_amdgcn_mfma_f32_16x16x32_bf16(af[mt], bfr[1], acc[mt][1], 0, 0, 0);
        }
        __builtin_amdgcn_s_setprio(0);
        __builtin_amdgcn_s_barrier();

        // ---- phase 1: read bf23; stage B(kt+3); counted vmcnt; tile barrier
        bfr[2] = *(const bf16x8*)(&Bs[buf][(wn * 4 + 2) * 512 + lane * 8]);
        bfr[3] = *(const bf16x8*)(&Bs[buf][(wn * 4 + 3) * 512 + lane * 8]);
        if (pre) stageB(kt + 3);
        __builtin_amdgcn_s_barrier();
        asm volatile("s_waitcnt lgkmcnt(0)" ::: "memory");
        __builtin_amdgcn_sched_barrier(0);
        __builtin_amdgcn_s_setprio(1);
#pragma unroll
        for (int mt = 0; mt < MT; mt++) {
            acc[mt][2] = __builtin_amdgcn_mfma_f32_16x16x32_bf16(af[mt], bfr[2], acc[mt][2], 0, 0, 0);
            acc[mt][3] = __builtin_amdgcn_mfma_f32_16x16x32_bf16(af[mt], bfr[3], acc[mt][3], 0, 0, 0);
        }
        __builtin_amdgcn_s_setprio(0);
        // ensure tile kt+1 landed before anyone reads it (never drain to 0 mid-loop)
        if (kt + 4 <= NT) {
            if constexpr (L == 4) asm volatile("s_waitcnt vmcnt(8)" ::: "memory");
            else                  asm volatile("s_waitcnt vmcnt(6)" ::: "memory");
        } else if (kt + 3 == NT) {
            if constexpr (L == 4) asm volatile("s_waitcnt vmcnt(4)" ::: "memory");
            else                  asm volatile("s_waitcnt vmcnt(3)" ::: "memory");
        } else if (kt + 2 == NT) {
            asm volatile("s_waitcnt vmcnt(0)" ::: "memory");
        }
        __builtin_amdgcn_s_barrier();
    }

    const void* bp = (store_mode == 3) ? (p == 0 ? bias0 : p == 1 ? bias1 : bias2)
                                       : bias0;
#pragma unroll
    for (int mt = 0; mt < MT; mt++) {
#pragma unroll
        for (int r = 0; r < 4; r++) {
            int m = m0 + wm * (BMt / 2) + mt * 16 + quad * 4 + r;
#pragma unroll
            for (int nt = 0; nt < 4; nt++) {
                int n = n0 + wn * 64 + nt * 16 + l15;
                float v = acc[mt][nt][r];
                if (bp) v += ldf(bp, (size_t)(n & 2047), fin);
                if (store_mode == 3) {
                    ((u16*)C)[(size_t)p * 8388608 + (size_t)m * 2048 + (n & 2047)] = f2bf(v);
                } else {
                    if (fin) ((float*)C)[(size_t)m * ldc + n] = v;
                    else     ((u16*)C)[(size_t)m * ldc + n] = f2bf(v);
                }
            }
        }
    }
}

// ---------------------------------------------------------------------------
// RoPE: one thread owns (b,s, 4 consecutive d2) and applies to all 16 heads of
// Q and K. 64x fewer transcendentals than per-element; ushort4 loads/stores.
// Per-element math identical to the old kernel (powf/sincosf/f2bf) -> bit-identical.
__global__ void k_rope3(u16* __restrict__ Q, u16* __restrict__ K) {
    int idx = blockIdx.x * 256 + threadIdx.x;    // 65536 threads
    int d2g = idx & 15;                          // 4-wide d2 group
    int rs  = idx >> 4;                          // b*S + s  (0..4095)
    int s   = rs & (S_ - 1);
    float cs[4], sn[4];
#pragma unroll
    for (int j = 0; j < 4; j++) {
        int d2 = d2g * 4 + j;
        float inv = powf(10000.f, -(float)d2 * (1.f / 64.f));
        float fr = (float)s * inv;
        sincosf(fr, &sn[j], &cs[j]);
    }
#pragma unroll
    for (int h = 0; h < H_; h++) {
        size_t base = ((size_t)(rs * H_ + h)) << 7;
#pragma unroll
        for (int a = 0; a < 2; a++) {
            u16* Y = a ? K : Q;
            ushort4 lo = *(const ushort4*)(Y + base + d2g * 4);
            ushort4 hi = *(const ushort4*)(Y + base + 64 + d2g * 4);
            ushort4 lo2, hi2;
            {
                float t0 = bf2f(lo.x), t1 = bf2f(hi.x);
                lo2.x = f2bf(t0 * cs[0] - t1 * sn[0]); hi2.x = f2bf(t1 * cs[0] + t0 * sn[0]);
            }
            {
                float t0 = bf2f(lo.y), t1 = bf2f(hi.y);
                lo2.y = f2bf(t0 * cs[1] - t1 * sn[1]); hi2.y = f2bf(t1 * cs[1] + t0 * sn[1]);
            }
            {
                float t0 = bf2f(lo.z), t1 = bf2f(hi.z);
                lo2.z = f2bf(t0 * cs[2] - t1 * sn[2]); hi2.z = f2bf(t1 * cs[2] + t0 * sn[2]);
            }
            {
                float t0 = bf2f(lo.w), t1 = bf2f(hi.w);
                lo2.w = f2bf(t0 * cs[3] - t1 * sn[3]); hi2.w = f2bf(t1 * cs[3] + t0 * sn[3]);
            }
            *(ushort4*)(Y + base + d2g * 4) = lo2;
            *(ushort4*)(Y + base + 64 + d2g * 4) = hi2;
        }
    }
}

// ---------------------------------------------------------------------------
// Vb [B,S,H*D] -> Vt [B*H*D, S]
__global__ void k_transpose_v(const u16* __restrict__ Vb, u16* __restrict__ Vt) {
    __shared__ u16 t[32][33];
    int s0 = blockIdx.x * 32;
    int n0 = blockIdx.y * 32;
    int b  = blockIdx.z;
    int tx = threadIdx.x & 31, ty = threadIdx.x >> 5;
#pragma unroll
    for (int r = 0; r < 4; r++)
        t[ty + r * 8][tx] = Vb[((size_t)(b * S_ + s0 + ty + r * 8)) * HD_ + n0 + tx];
    __syncthreads();
#pragma unroll
    for (int r = 0; r < 4; r++)
        Vt[((size_t)(b * HD_ + n0 + ty + r * 8)) * S_ + s0 + tx] = t[tx][ty + r * 8];
}

// ---------------------------------------------------------------------------
// MFMA flash attention: 64-query tiles, LDS-staged K/V, swapped QK^T softmax
// (lane-local row, 4 shuffles/chunk). r14: depth-2 K/V register prefetch
// (even/odd sets) + XCD-contiguous block swizzle (4 bh per XCD).
#define KS_ST 136
#define VT_ST 72
#define SCALE_ 0.088388347648318447f

__global__ __launch_bounds__(256, 3) void k_flash7(
    const u16* __restrict__ Q, const u16* __restrict__ K,
    const u16* __restrict__ Vt, u16* __restrict__ O) {
    __shared__ __align__(16) u16 Ks[64 * KS_ST];    // 17408 B
    __shared__ __align__(16) u16 Vs[128 * VT_ST];   // 18432 B
    __shared__ __align__(16) u16 Ps[64 * VT_ST];    //  9216 B
    int tid = threadIdx.x;
    int w = tid >> 6, lane = tid & 63;
    int l15 = lane & 15, quad = lane >> 4;

    // XCD-contiguous swizzle: 1024 blocks, 4 bh per XCD; heavy q-tiles first.
    int lin = blockIdx.y * 32 + blockIdx.x;
    int wg  = (lin & 7) * 128 + (lin >> 3);
    int bh = wg >> 5, b = bh >> 4, h = bh & 15;
    int t = 31 - (wg & 31);
    int q0 = t * 64;

    int krow[4], kd8[4], vd[4], vkg[4];
#pragma unroll
    for (int it = 0; it < 4; it++) {
        int idx = it * 256 + tid;
        krow[it] = idx >> 4; kd8[it] = (idx & 15) * 8;
        vd[it] = idx >> 3;   vkg[it] = (idx & 7) * 8;
    }

    bf16x8 qf[4];
    size_t baseQ = ((size_t)(b * S_ + q0 + w * 16 + l15)) * HD_ + h * D_;
#pragma unroll
    for (int ks = 0; ks < 4; ks++)
        qf[ks] = *(const bf16x8*)(Q + baseQ + ks * 32 + quad * 8);

    f32x4 of[8];
#pragma unroll
    for (int nt = 0; nt < 8; nt++)
#pragma unroll
        for (int r = 0; r < 4; r++) of[nt][r] = 0.f;
    float mreg = -30000.f, lreg = 0.f;
    int qrow = q0 + w * 16 + l15;

    int nch = t + 1;

    // depth-2 register prefetch: A = even chunks, B = odd chunks
    bf16x8 kpA[4], vpA[4], kpB[4], vpB[4];
#pragma unroll
    for (int it = 0; it < 4; it++) {
        kpA[it] = *(const bf16x8*)(K + ((size_t)(b * S_ + krow[it])) * HD_ + h * D_ + kd8[it]);
        vpA[it] = *(const bf16x8*)(Vt + ((size_t)(bh * 128 + vd[it])) * S_ + vkg[it]);
    }
    if (nch > 1) {
#pragma unroll
        for (int it = 0; it < 4; it++) {
            kpB[it] = *(const bf16x8*)(K + ((size_t)(b * S_ + 64 + krow[it])) * HD_ + h * D_ + kd8[it]);
            vpB[it] = *(const bf16x8*)(Vt + ((size_t)(bh * 128 + vd[it])) * S_ + 64 + vkg[it]);
        }
    }

    for (int c = 0; c < nch; c++) {
        int k0 = c * 64;
        __syncthreads();
        if ((c & 1) == 0) {
#pragma unroll
            for (int it = 0; it < 4; it++) {
                *(bf16x8*)(Ks + krow[it] * KS_ST + kd8[it]) = kpA[it];
                *(bf16x8*)(Vs + vd[it] * VT_ST + vkg[it]) = vpA[it];
            }
        } else {
#pragma unroll
            for (int it = 0; it < 4; it++) {
                *(bf16x8*)(Ks + krow[it] * KS_ST + kd8[it]) = kpB[it];
                *(bf16x8*)(Vs + vd[it] * VT_ST + vkg[it]) = vpB[it];
            }
        }
        __syncthreads();
        if (c + 2 < nch) {
            int k2 = k0 + 128;
            if ((c & 1) == 0) {
#pragma unroll
                for (int it = 0; it < 4; it++) {
                    kpA[it] = *(const bf16x8*)(K + ((size_t)(b * S_ + k2 + krow[it])) * HD_ + h * D_ + kd8[it]);
                    vpA[it] = *(const bf16x8*)(Vt + ((size_t)(bh * 128 + vd[it])) * S_ + k2 + vkg[it]);
                }
            } else {
#pragma unroll
                for (int it = 0; it < 4; it++) {
                    kpB[it] = *(const bf16x8*)(K + ((size_t)(b * S_ + k2 + krow[it])) * HD_ + h * D_ + kd8[it]);
                    vpB[it] = *(const bf16x8*)(Vt + ((size_t)(bh * 128 + vd[it])) * S_ + k2 + vkg[it]);
                }
            }
        }

        f32x4 sf[4];
#pragma unroll
        for (int nt = 0; nt < 4; nt++)
#pragma unroll
            for (int r = 0; r < 4; r++) sf[nt][r] = 0.f;
#pragma unroll
        for (int ks = 0; ks < 4; ks++) {
            int koff = ks * 32 + quad * 8;
            bf16x8 qa = qf[ks];
#pragma unroll
            for (int nt = 0; nt < 4; nt++) {
                bf16x8 kb = *(const bf16x8*)(Ks + (nt * 16 + l15) * KS_ST + koff);
                sf[nt] = __builtin_amdgcn_mfma_f32_16x16x32_bf16(kb, qa, sf[nt], 0, 0, 0);
            }
        }

#pragma unroll
        for (int nt = 0; nt < 4; nt++) {
            int keyb = k0 + nt * 16 + quad * 4;
#pragma unroll
            for (int r = 0; r < 4; r++) {
                float sv = sf[nt][r] * SCALE_;
                sf[nt][r] = (keyb + r > qrow) ? -30000.f : sv;
            }
        }

        float t0 = fmaxf(fmaxf(sf[0][0], sf[0][1]), fmaxf(sf[0][2], sf[0][3]));
        float t1 = fmaxf(fmaxf(sf[1][0], sf[1][1]), fmaxf(sf[1][2], sf[1][3]));
        float t2 = fmaxf(fmaxf(sf[2][0], sf[2][1]), fmaxf(sf[2][2], sf[2][3]));
        float t3 = fmaxf(fmaxf(sf[3][0], sf[3][1]), fmaxf(sf[3][2], sf[3][3]));
        float cmax = fmaxf(fmaxf(t0, t1), fmaxf(t2, t3));
        cmax = fmaxf(cmax, __shfl_xor(cmax, 16, 64));
        cmax = fmaxf(cmax, __shfl_xor(cmax, 32, 64));
        float mnew = fmaxf(mreg, cmax);
        float a = __expf(mreg - mnew);
        mreg = mnew;
#pragma unroll
        for (int nt = 0; nt < 4; nt++)
#pragma unroll
            for (int r = 0; r < 4; r++)
                sf[nt][r] = __expf(sf[nt][r] - mnew);
        float s0 = (sf[0][0] + sf[0][1]) + (sf[0][2] + sf[0][3]);
        float s1 = (sf[1][0] + sf[1][1]) + (sf[1][2] + sf[1][3]);
        float s2 = (sf[2][0] + sf[2][1]) + (sf[2][2] + sf[2][3]);
        float s3 = (sf[3][0] + sf[3][1]) + (sf[3][2] + sf[3][3]);
        float psum = (s0 + s1) + (s2 + s3);
        psum += __shfl_xor(psum, 16, 64);
        psum += __shfl_xor(psum, 32, 64);
        lreg = lreg * a + psum;

        float al[4];
#pragma unroll
        for (int r = 0; r < 4; r++) al[r] = __shfl(a, quad * 4 + r, 16);

#pragma unroll
        for (int nt = 0; nt < 4; nt++)
#pragma unroll
            for (int r = 0; r < 4; r++)
                Ps[(w * 16 + l15) * VT_ST + nt * 16 + quad * 4 + r] = f2bf(sf[nt][r]);
#pragma unroll
        for (int nt = 0; nt < 8; nt++)
#pragma unroll
            for (int r = 0; r < 4; r++) of[nt][r] *= al[r];

#pragma unroll
        for (int ks2 = 0; ks2 < 2; ks2++) {
            int koff = ks2 * 32 + quad * 8;
            bf16x8 pa = *(const bf16x8*)(Ps + (w * 16 + l15) * VT_ST + koff);
#pragma unroll
            for (int nt = 0; nt < 8; nt++) {
                bf16x8 vb = *(const bf16x8*)(Vs + (nt * 16 + l15) * VT_ST + koff);
                of[nt] = __builtin_amdgcn_mfma_f32_16x16x32_bf16(pa, vb, of[nt], 0, 0, 0);
            }
        }
    }

    float linv = 1.f / lreg;
    float inv[4];
#pragma unroll
    for (int r = 0; r < 4; r++) inv[r] = __shfl(linv, quad * 4 + r, 16);
    int rowb = q0 + w * 16 + quad * 4;
#pragma unroll
    for (int r = 0; r < 4; r++) {
        size_t base = ((size_t)(b * S_ + rowb + r)) * HD_ + h * D_;
#pragma unroll
        for (int nt = 0; nt < 8; nt++)
            O[base + nt * 16 + l15] = f2bf(of[nt][r] * inv[r]);
    }
}

// ---------------------------------------------------------------------------
extern "C" void kernel_launch(void* const* d_in, const int* in_sizes, int n_in,
                              void* d_out, int out_size, void* d_ws, size_t ws_size,
                              hipStream_t stream) {
    const void* x    = d_in[0];
    const void* mask = d_in[1];
    const void* Wq = d_in[2];  const void* bq = d_in[3];
    const void* Aq = d_in[4];  const void* Bq = d_in[5];
    const void* Wk = d_in[6];  const void* bk = d_in[7];
    const void* Ak = d_in[8];  const void* Bk = d_in[9];
    const void* Wv = d_in[10]; const void* bv = d_in[11];
    const void* Av = d_in[12]; const void* Bv = d_in[13];
    const void* Wo = d_in[14]; const void* bo = d_in[15];
    const void* Ao = d_in[16]; const void* Bo = d_in[17];

    char* ws = (char*)d_ws;
    const long MB = 1 << 20;
    int* flags = (int*)ws;
    u16* Xb    = (u16*)(ws + 1  * MB);   // 16 MB
    u16* Acat  = (u16*)(ws + 17 * MB);   // 2 MB
    u16* Bmcat = (u16*)(ws + 19 * MB);   // 2 MB
    u16* hg3   = (u16*)(ws + 21 * MB);   // 3 MB  [M,384] bf16
    u16* hgo   = (u16*)(ws + 24 * MB);   // 1 MB  [M,128] bf16
    u16* Qb    = (u16*)(ws + 25 * MB);   // 16 MB; hg3f pre-lives here; Wob after flash
    u16* Kb    = (u16*)(ws + 41 * MB);   // 16 MB; hgof after flash
    u16* Vb    = (u16*)(ws + 57 * MB);   // 16 MB; Ob after transpose
    u16* Vt    = (u16*)(ws + 73 * MB);   // 16 MB (written after Wcat dead)
    u16* Wcat  = (u16*)(ws + 73 * MB);   // 24 MB [6144][2048]; dead after QKV GEMM (end 97 MB)
    float* hg3f = (float*)Qb;            // 6 MB  [M,384] f32 (dead before QKV writes Qb)
    float* hgof = (float*)Kb;            // 2 MB  [M,128] f32 (Kb dead after flash)
    u16* Wob   = Qb;                     // Wo converted after flash (Qb dead)
    u16* Ob    = Vb;                     // Vb dead after transpose

    k_detect<<<1, 64, 0, stream>>>(x, flags);
    k_zero<<<1536, 256, 0, stream>>>((float4*)hg3f, 393216);     // 4096*384 f32
    const long NCVT = NX_ + 8 * NA1_ + 3 * NW_;   // 23068672
    k_cvt_all<<<NCVT / 1024, 256, 0, stream>>>(
        x, Aq, Ak, Av, Ao, Bq, Bk, Bv, Bo, Wq, Wk, Wv,
        Xb, Acat, Bmcat, Wcat, flags);

    // qkv LoRA-h: hg3f[m][p*128+er] via split-K x4, then cvt to bf16
    k_gemm_sk<<<dim3(3, M_ / BM_, 4), 256, 0, stream>>>(
        Xb, E_, Acat, E_, E_, mask, hg3f, 384, flags);
    k_cvtf<<<1536, 256, 0, stream>>>(hg3f, hg3, 1572864);

    // fused QKV projection: r11 pipeline, BMt=256, grid (24,16) = 384 blocks
    k_gemm8p<256><<<dim3(6144 / 256, M_ / 256), 512, 0, stream>>>(
        Xb, E_, Wcat, E_, E_, hg3, 384, Bmcat, KL_,
        bq, bk, bv, Qb, HD_, 3, flags);

    k_rope3<<<256, 256, 0, stream>>>(Qb, Kb);
    k_transpose_v<<<dim3(S_ / 32, HD_ / 32, B_), 256, 0, stream>>>(Vb, Vt);

    k_flash7<<<dim3(32, 32), 256, 0, stream>>>(Qb, Kb, Vt, Ob);

    // out-proj LoRA-h via split-K x4 (into dead Kb region), Wo cvt (dead Qb region)
    k_zero<<<512, 256, 0, stream>>>((float4*)hgof, 131072);      // 4096*128 f32
    k_cvt<<<NW_ / 1024, 256, 0, stream>>>(Wo, Wob, (int)NW_, flags);
    k_gemm_sk<<<dim3(1, M_ / BM_, 4), 256, 0, stream>>>(
        Ob, HD_, Acat + 3 * NA1_, E_, E_, mask, hgof, KL_, flags);
    k_cvtf<<<512, 256, 0, stream>>>(hgof, hgo, 524288);

    // output projection: r11 pipeline, BMt=128, grid (8,32) = 256 blocks
    k_gemm8p<128><<<dim3(HD_ / 256, M_ / 128), 512, 0, stream>>>(
        Ob, HD_, Wob, E_, E_, hgo, KL_, Bmcat + 3 * NA1_, KL_,
        bo, nullptr, nullptr, d_out, HD_, 2, flags);
}

// Round 9
// 719.987 us; speedup vs baseline: 1.0272x; 1.0013x over previous
//
#include <hip/hip_runtime.h>

// RStarcoderAttention: MoE-LoRA QKV proj + RoPE + causal flash attention + LoRA out proj.
// B=2 S=2048 E=2048 H=16 D=128 NE=8 R=16. fp32 accumulation everywhere.
// Round 15: flash load-balance. Pair q-tiles (t, 31-t) in one block -> every block
// has exactly 33 chunks; grid 512 blocks = 2/CU, ALL co-resident, zero tail
// (r14 counters: Occupancy 13.6% of 37.5% declared = CUs idle ~63% on imbalance).
// Flash inner loop, GEMMs (r11 k_gemm8p, QKV 210us), rope3, split-K LoRA, cvt:
// all unchanged from r14. Bit-exact per query row -> absmax stays 0.3049316.

#define B_ 2
#define S_ 2048
#define E_ 2048
#define H_ 16
#define D_ 128
#define NE_ 8
#define R_ 16
#define HD_ 2048
#define M_ 4096          // B*S tokens
#define KL_ 128          // NE*R

typedef unsigned short u16;
typedef unsigned int u32;
typedef __attribute__((ext_vector_type(8))) short bf16x8;
typedef __attribute__((ext_vector_type(4))) float f32x4;

typedef const __attribute__((address_space(1))) void gvoid_t;
typedef __attribute__((address_space(3))) void svoid_t;

__device__ __forceinline__ float bf2f(u16 u) {
    union { u32 i; float f; } v; v.i = ((u32)u) << 16; return v.f;
}
__device__ __forceinline__ u16 f2bf(float f) {
    union { float f; u32 i; } v; v.f = f;
    u32 x = v.i;
    return (u16)((x + 0x7fffu + ((x >> 16) & 1u)) >> 16);   // RNE
}
__device__ __forceinline__ float ldf(const void* p, size_t i, int f) {
    return f ? ((const float*)p)[i] : bf2f(((const u16*)p)[i]);
}
__device__ __forceinline__ float4 ld4(const void* p, size_t i, int f) {
    if (f) return *(const float4*)((const float*)p + i);
    ushort4 v = *(const ushort4*)((const u16*)p + i);
    return make_float4(bf2f(v.x), bf2f(v.y), bf2f(v.z), bf2f(v.w));
}

// ---------------------------------------------------------------------------
__global__ void k_detect(const void* __restrict__ x, int* __restrict__ flags) {
    __shared__ int votes[2];
    int tid = threadIdx.x;
    if (tid < 2) votes[tid] = 0;
    __syncthreads();
    const u32* p = (const u32*)x;
    int bad = 0, tot = 0;
    for (int i = tid; i < 4096; i += 64) {
        u32 lo = p[i] & 0xffffu;
        if (lo) {
            tot++;
            int e = (int)((lo >> 7) & 0xffu);
            if (e < 100 || e > 150) bad++;
        }
    }
    atomicAdd(&votes[0], bad);
    atomicAdd(&votes[1], tot);
    __syncthreads();
    if (tid == 0) flags[0] = (votes[1] > 0 && votes[0] * 10 > votes[1] * 3) ? 1 : 0;
}

// ---------------------------------------------------------------------------
// Generic fp32/bf16 -> bf16 conversion (4 el/thread).
__global__ void k_cvt(const void* __restrict__ src, u16* __restrict__ dst, int n,
                      const int* __restrict__ flags) {
    int fin = flags[0];
    int i = (blockIdx.x * 256 + threadIdx.x) * 4;
    if (i >= n) return;
    float4 v = ld4(src, i, fin);
    ushort4 o;
    o.x = f2bf(v.x); o.y = f2bf(v.y); o.z = f2bf(v.z); o.w = f2bf(v.w);
    *(ushort4*)(dst + i) = o;
}

// f32 -> bf16 (4 el/thread), always-f32 source.
__global__ void k_cvtf(const float* __restrict__ src, u16* __restrict__ dst, int n) {
    int i = (blockIdx.x * 256 + threadIdx.x) * 4;
    if (i >= n) return;
    float4 v = *(const float4*)(src + i);
    ushort4 o;
    o.x = f2bf(v.x); o.y = f2bf(v.y); o.z = f2bf(v.z); o.w = f2bf(v.w);
    *(ushort4*)(dst + i) = o;
}

// zero f32 buffer (float4/thread)
__global__ void k_zero(float4* __restrict__ p, int n4) {
    int i = blockIdx.x * 256 + threadIdx.x;
    if (i < n4) p[i] = make_float4(0.f, 0.f, 0.f, 0.f);
}

// ---------------------------------------------------------------------------
// Batched conversion: x -> Xb; Aq..Ao -> Acat; Bq..Bo -> Bmcat; Wq/Wk/Wv -> Wcat.
#define NX_  8388608L   // M*E
#define NA1_ 262144L    // KL*E (also HD*KL)
#define NW_  4194304L   // E*HD
__global__ void k_cvt_all(
    const void* __restrict__ x,
    const void* __restrict__ Aq, const void* __restrict__ Ak,
    const void* __restrict__ Av, const void* __restrict__ Ao,
    const void* __restrict__ Bq, const void* __restrict__ Bk,
    const void* __restrict__ Bv, const void* __restrict__ Bo,
    const void* __restrict__ Wq, const void* __restrict__ Wk,
    const void* __restrict__ Wv,
    u16* __restrict__ Xb, u16* __restrict__ Acat, u16* __restrict__ Bmcat,
    u16* __restrict__ Wcat,
    const int* __restrict__ flags) {
    int fin = flags[0];
    long i = (long)(blockIdx.x * 256 + threadIdx.x) * 4;
    const void* src; u16* dst; long off;
    if (i < NX_) { src = x; dst = Xb; off = i; }
    else if (i < NX_ + 4 * NA1_) {
        long j = i - NX_; int p = (int)(j >> 18); off = j & (NA1_ - 1);
        src = (p == 0) ? Aq : (p == 1) ? Ak : (p == 2) ? Av : Ao;
        dst = Acat + (long)p * NA1_;
    } else if (i < NX_ + 8 * NA1_) {
        long j = i - NX_ - 4 * NA1_; int p = (int)(j >> 18); off = j & (NA1_ - 1);
        src = (p == 0) ? Bq : (p == 1) ? Bk : (p == 2) ? Bv : Bo;
        dst = Bmcat + (long)p * NA1_;
    } else {
        long j = i - NX_ - 8 * NA1_; int p = (int)(j / NW_); off = j - (long)p * NW_;
        src = (p == 0) ? Wq : (p == 1) ? Wk : Wv;
        dst = Wcat + (long)p * NW_;
    }
    float4 v = ld4(src, off, fin);
    ushort4 o;
    o.x = f2bf(v.x); o.y = f2bf(v.y); o.z = f2bf(v.z); o.w = f2bf(v.w);
    *(ushort4*)(dst + off) = o;
}

// ---------------------------------------------------------------------------
// Split-K GEMM for the small LoRA projections: Cf[m][n] += mask * sum_k A*B.
#define BM_ 128
#define BN_ 128
#define BK_ 64

__global__ __launch_bounds__(256, 2) void k_gemm_sk(
    const u16* __restrict__ A, int lda,
    const u16* __restrict__ Bw, int ldb, int K,
    const void* __restrict__ mask,
    float* __restrict__ Cf, int ldc,
    const int* __restrict__ flags) {
    __shared__ __align__(16) u16 As[BM_ * BK_];   // 16 KB
    __shared__ __align__(16) u16 Bs[BN_ * BK_];   // 16 KB
    int fin = flags[0];
    int tid = threadIdx.x;
    int w = tid >> 6, lane = tid & 63;
    int l15 = lane & 15, quad = lane >> 4;
    int wm = w >> 1, wn = w & 1;
    int m0 = blockIdx.y * BM_, n0 = blockIdx.x * BN_;
    int lrow = lane >> 3;          // 0..7
    int lcol = (lane & 7) * 8;     // 16B granule

    f32x4 acc[4][4];
#pragma unroll
    for (int mt = 0; mt < 4; mt++)
#pragma unroll
        for (int nt = 0; nt < 4; nt++)
#pragma unroll
            for (int r = 0; r < 4; r++) acc[mt][nt][r] = 0.f;

    int iters = (K / BK_) / gridDim.z;
    int it0 = blockIdx.z * iters;
    for (int it = it0; it < it0 + iters; it++) {
        int kb = it * BK_;
        __syncthreads();
#pragma unroll
        for (int i = 0; i < 4; i++) {
            int rowb = (w * 4 + i) * 8;
            int r = rowb + lrow;
            __builtin_amdgcn_global_load_lds(
                (gvoid_t*)(A + (size_t)(m0 + r) * lda + kb + lcol),
                (svoid_t*)(As + rowb * BK_), 16, 0, 0);
            __builtin_amdgcn_global_load_lds(
                (gvoid_t*)(Bw + (size_t)(n0 + r) * ldb + kb + lcol),
                (svoid_t*)(Bs + rowb * BK_), 16, 0, 0);
        }
        __syncthreads();
#pragma unroll
        for (int kk = 0; kk < 2; kk++) {
            int ko = kk * 32 + quad * 8;
            bf16x8 af[4], bf[4];
#pragma unroll
            for (int mt = 0; mt < 4; mt++)
                af[mt] = *(const bf16x8*)(As + (wm * 64 + mt * 16 + l15) * BK_ + ko);
#pragma unroll
            for (int nt = 0; nt < 4; nt++)
                bf[nt] = *(const bf16x8*)(Bs + (wn * 64 + nt * 16 + l15) * BK_ + ko);
#pragma unroll
            for (int mt = 0; mt < 4; mt++)
#pragma unroll
                for (int nt = 0; nt < 4; nt++)
                    acc[mt][nt] = __builtin_amdgcn_mfma_f32_16x16x32_bf16(
                        af[mt], bf[nt], acc[mt][nt], 0, 0, 0);
        }
    }

#pragma unroll
    for (int mt = 0; mt < 4; mt++) {
#pragma unroll
        for (int r = 0; r < 4; r++) {
            int m = m0 + wm * 64 + mt * 16 + quad * 4 + r;
#pragma unroll
            for (int nt = 0; nt < 4; nt++) {
                int n = n0 + wn * 64 + nt * 16 + l15;
                float v = acc[mt][nt][r] * ldf(mask, (size_t)m * NE_ + ((n & 127) >> 4), fin);
                atomicAdd(&Cf[(size_t)m * ldc + n], v);
            }
        }
    }
}

// ---------------------------------------------------------------------------
// Big GEMM (r11, best measured). Tile BMt x 256, BK=32, 8 waves (2m x 4n), 4 LDS
// buffers, 3-tile-deep prefetch, counted vmcnt once per K-tile. LDS subtiles
// fragment-native (16 rows x 32 k, lane-linear -> conflict-free ds_read_b128).
// store_mode 2: C f32/bf16 by fin; store_mode 3: fused QKV (p = n0>>11 selects
// bias / lora segment / output third).
template <int BMt>
__global__ __launch_bounds__(512, 2) void k_gemm8p(
    const u16* __restrict__ A, int lda,
    const u16* __restrict__ Bw, int ldb, int K1,
    const u16* __restrict__ A2, int lda2,
    const u16* __restrict__ B2, int K2,
    const void* __restrict__ bias0, const void* __restrict__ bias1,
    const void* __restrict__ bias2,
    void* __restrict__ C, int ldc, int store_mode,
    const int* __restrict__ flags) {
    constexpr int MT  = BMt / 32;    // m-frags per wave
    constexpr int NSA = BMt / 16;    // A subtiles per K-tile
    constexpr int LA  = BMt / 128;   // A stage loads per wave per tile
    constexpr int L   = LA + 2;      // total stage loads per wave per tile
    __shared__ __align__(16) u16 As[4][NSA * 512];   // 4 x (BMt*32) el
    __shared__ __align__(16) u16 Bs[4][16 * 512];    // 4 x 16 KB
    int fin = flags[0];
    int tid = threadIdx.x;
    int w = tid >> 6, lane = tid & 63;
    int l15 = lane & 15, quad = lane >> 4;
    int wm = w >> 2, wn = w & 3;             // 2 x 4 wave grid

    // XCD-aware swizzle (grid sizes are multiples of 8)
    int lin = blockIdx.y * gridDim.x + blockIdx.x;
    int cpx = (gridDim.x * gridDim.y) >> 3;
    int wg = (lin & 7) * cpx + (lin >> 3);
    int m0 = (wg / gridDim.x) * BMt;
    int n0 = (wg % gridDim.x) * 256;

    int p = (store_mode == 3) ? (n0 >> 11) : 0;
    const u16* A2p = A2 + p * 128;
    const u16* B2p = B2 + (long)p * NA1_;
    int nloc = (store_mode == 3) ? (n0 & 2047) : n0;

    int nk1 = K1 >> 5;
    int NT = nk1 + (K2 >> 5);

    f32x4 acc[MT][4];
#pragma unroll
    for (int mt = 0; mt < MT; mt++)
#pragma unroll
        for (int nt = 0; nt < 4; nt++)
#pragma unroll
            for (int r = 0; r < 4; r++) acc[mt][nt][r] = 0.f;

    auto stageA = [&](int kt) {
        const u16* pa; size_t sa; int kb;
        if (kt < nk1) { pa = A;   sa = (size_t)lda;  kb = kt * 32; }
        else          { pa = A2p; sa = (size_t)lda2; kb = (kt - nk1) * 32; }
        int buf = kt & 3;
#pragma unroll
        for (int j = 0; j < LA; j++) {
            int rb = w * LA + j;
            __builtin_amdgcn_global_load_lds(
                (gvoid_t*)(pa + (size_t)(m0 + rb * 16 + l15) * sa + kb + quad * 8),
                (svoid_t*)(&As[buf][rb * 512]), 16, 0, 0);
        }
    };
    auto stageB = [&](int kt) {
        const u16* pb; size_t sb; int kb, nb;
        if (kt < nk1) { pb = Bw;  sb = (size_t)ldb; kb = kt * 32;          nb = n0; }
        else          { pb = B2p; sb = (size_t)K2;  kb = (kt - nk1) * 32;  nb = nloc; }
        int buf = kt & 3;
#pragma unroll
        for (int j = 0; j < 2; j++) {
            int rb = w * 2 + j;
            __builtin_amdgcn_global_load_lds(
                (gvoid_t*)(pb + (size_t)(nb + rb * 16 + l15) * sb + kb + quad * 8),
                (svoid_t*)(&Bs[buf][rb * 512]), 16, 0, 0);
        }
    };

    // prologue: tiles 0,1,2 fully staged (3L loads in flight), wait tile 0
    stageA(0); stageB(0);
    stageA(1); stageB(1);
    stageA(2); stageB(2);
    if constexpr (L == 4) asm volatile("s_waitcnt vmcnt(8)" ::: "memory");
    else                  asm volatile("s_waitcnt vmcnt(6)" ::: "memory");
    __builtin_amdgcn_s_barrier();

    for (int kt = 0; kt < NT; kt++) {
        int buf = kt & 3;
        bool pre = (kt + 3 < NT);

        // ---- phase 0: read af (held through both phases) + bf01; stage A(kt+3)
        bf16x8 af[MT], bfr[4];
#pragma unroll
        for (int mt = 0; mt < MT; mt++)
            af[mt] = *(const bf16x8*)(&As[buf][(wm * MT + mt) * 512 + lane * 8]);
        bfr[0] = *(const bf16x8*)(&Bs[buf][(wn * 4 + 0) * 512 + lane * 8]);
        bfr[1] = *(const bf16x8*)(&Bs[buf][(wn * 4 + 1) * 512 + lane * 8]);
        if (pre) stageA(kt + 3);
        __builtin_amdgcn_s_barrier();
        asm volatile("s_waitcnt lgkmcnt(0)" ::: "memory");
        __builtin_amdgcn_sched_barrier(0);
        __builtin_amdgcn_s_setprio(1);
#pragma unroll
        for (int mt = 0; mt < MT; mt++) {
            acc[mt][0] = __builtin_amdgcn_mfma_f32_16x16x32_bf16(af[mt], bfr[0], acc[mt][0], 0, 0, 0);
            acc[mt][1] = __builtin_amdgcn_mfma_f32_16x16x32_bf16(af[mt], bfr[1], acc[mt][1], 0, 0, 0);
        }
        __builtin_amdgcn_s_setprio(0);
        __builtin_amdgcn_s_barrier();

        // ---- phase 1: read bf23; stage B(kt+3); counted vmcnt; tile barrier
        bfr[2] = *(const bf16x8*)(&Bs[buf][(wn * 4 + 2) * 512 + lane * 8]);
        bfr[3] = *(const bf16x8*)(&Bs[buf][(wn * 4 + 3) * 512 + lane * 8]);
        if (pre) stageB(kt + 3);
        __builtin_amdgcn_s_barrier();
        asm volatile("s_waitcnt lgkmcnt(0)" ::: "memory");
        __builtin_amdgcn_sched_barrier(0);
        __builtin_amdgcn_s_setprio(1);
#pragma unroll
        for (int mt = 0; mt < MT; mt++) {
            acc[mt][2] = __builtin_amdgcn_mfma_f32_16x16x32_bf16(af[mt], bfr[2], acc[mt][2], 0, 0, 0);
            acc[mt][3] = __builtin_amdgcn_mfma_f32_16x16x32_bf16(af[mt], bfr[3], acc[mt][3], 0, 0, 0);
        }
        __builtin_amdgcn_s_setprio(0);
        // ensure tile kt+1 landed before anyone reads it (never drain to 0 mid-loop)
        if (kt + 4 <= NT) {
            if constexpr (L == 4) asm volatile("s_waitcnt vmcnt(8)" ::: "memory");
            else                  asm volatile("s_waitcnt vmcnt(6)" ::: "memory");
        } else if (kt + 3 == NT) {
            if constexpr (L == 4) asm volatile("s_waitcnt vmcnt(4)" ::: "memory");
            else                  asm volatile("s_waitcnt vmcnt(3)" ::: "memory");
        } else if (kt + 2 == NT) {
            asm volatile("s_waitcnt vmcnt(0)" ::: "memory");
        }
        __builtin_amdgcn_s_barrier();
    }

    const void* bp = (store_mode == 3) ? (p == 0 ? bias0 : p == 1 ? bias1 : bias2)
                                       : bias0;
#pragma unroll
    for (int mt = 0; mt < MT; mt++) {
#pragma unroll
        for (int r = 0; r < 4; r++) {
            int m = m0 + wm * (BMt / 2) + mt * 16 + quad * 4 + r;
#pragma unroll
            for (int nt = 0; nt < 4; nt++) {
                int n = n0 + wn * 64 + nt * 16 + l15;
                float v = acc[mt][nt][r];
                if (bp) v += ldf(bp, (size_t)(n & 2047), fin);
                if (store_mode == 3) {
                    ((u16*)C)[(size_t)p * 8388608 + (size_t)m * 2048 + (n & 2047)] = f2bf(v);
                } else {
                    if (fin) ((float*)C)[(size_t)m * ldc + n] = v;
                    else     ((u16*)C)[(size_t)m * ldc + n] = f2bf(v);
                }
            }
        }
    }
}

// ---------------------------------------------------------------------------
// RoPE: one thread owns (b,s, 4 consecutive d2) and applies to all 16 heads of
// Q and K. 64x fewer transcendentals than per-element; ushort4 loads/stores.
__global__ void k_rope3(u16* __restrict__ Q, u16* __restrict__ K) {
    int idx = blockIdx.x * 256 + threadIdx.x;    // 65536 threads
    int d2g = idx & 15;                          // 4-wide d2 group
    int rs  = idx >> 4;                          // b*S + s  (0..4095)
    int s   = rs & (S_ - 1);
    float cs[4], sn[4];
#pragma unroll
    for (int j = 0; j < 4; j++) {
        int d2 = d2g * 4 + j;
        float inv = powf(10000.f, -(float)d2 * (1.f / 64.f));
        float fr = (float)s * inv;
        sincosf(fr, &sn[j], &cs[j]);
    }
#pragma unroll
    for (int h = 0; h < H_; h++) {
        size_t base = ((size_t)(rs * H_ + h)) << 7;
#pragma unroll
        for (int a = 0; a < 2; a++) {
            u16* Y = a ? K : Q;
            ushort4 lo = *(const ushort4*)(Y + base + d2g * 4);
            ushort4 hi = *(const ushort4*)(Y + base + 64 + d2g * 4);
            ushort4 lo2, hi2;
            {
                float t0 = bf2f(lo.x), t1 = bf2f(hi.x);
                lo2.x = f2bf(t0 * cs[0] - t1 * sn[0]); hi2.x = f2bf(t1 * cs[0] + t0 * sn[0]);
            }
            {
                float t0 = bf2f(lo.y), t1 = bf2f(hi.y);
                lo2.y = f2bf(t0 * cs[1] - t1 * sn[1]); hi2.y = f2bf(t1 * cs[1] + t0 * sn[1]);
            }
            {
                float t0 = bf2f(lo.z), t1 = bf2f(hi.z);
                lo2.z = f2bf(t0 * cs[2] - t1 * sn[2]); hi2.z = f2bf(t1 * cs[2] + t0 * sn[2]);
            }
            {
                float t0 = bf2f(lo.w), t1 = bf2f(hi.w);
                lo2.w = f2bf(t0 * cs[3] - t1 * sn[3]); hi2.w = f2bf(t1 * cs[3] + t0 * sn[3]);
            }
            *(ushort4*)(Y + base + d2g * 4) = lo2;
            *(ushort4*)(Y + base + 64 + d2g * 4) = hi2;
        }
    }
}

// ---------------------------------------------------------------------------
// Vb [B,S,H*D] -> Vt [B*H*D, S]
__global__ void k_transpose_v(const u16* __restrict__ Vb, u16* __restrict__ Vt) {
    __shared__ u16 t[32][33];
    int s0 = blockIdx.x * 32;
    int n0 = blockIdx.y * 32;
    int b  = blockIdx.z;
    int tx = threadIdx.x & 31, ty = threadIdx.x >> 5;
#pragma unroll
    for (int r = 0; r < 4; r++)
        t[ty + r * 8][tx] = Vb[((size_t)(b * S_ + s0 + ty + r * 8)) * HD_ + n0 + tx];
    __syncthreads();
#pragma unroll
    for (int r = 0; r < 4; r++)
        Vt[((size_t)(b * HD_ + n0 + ty + r * 8)) * S_ + s0 + tx] = t[tx][ty + r * 8];
}

// ---------------------------------------------------------------------------
// MFMA flash attention, paired q-tiles. Grid (16,32) = 512 blocks, each block
// processes q-tiles t=31-pair (heavy, first) and t=pair: exactly 33 chunks per
// block -> 2 blocks/CU, all co-resident, perfectly balanced, zero tail.
// Inner loop = r14 flash7 (LDS-staged K/V, depth-2 reg prefetch, swapped-QK^T
// lane-local softmax). XCD-contiguous swizzle: 4 bh per XCD.
#define KS_ST 136
#define VT_ST 72
#define SCALE_ 0.088388347648318447f

__global__ __launch_bounds__(256, 3) void k_flash8(
    const u16* __restrict__ Q, const u16* __restrict__ K,
    const u16* __restrict__ Vt, u16* __restrict__ O) {
    __shared__ __align__(16) u16 Ks[64 * KS_ST];    // 17408 B
    __shared__ __align__(16) u16 Vs[128 * VT_ST];   // 18432 B
    __shared__ __align__(16) u16 Ps[64 * VT_ST];    //  9216 B
    int tid = threadIdx.x;
    int w = tid >> 6, lane = tid & 63;
    int l15 = lane & 15, quad = lane >> 4;

    // 512 blocks; XCD-contiguous (64 wg per XCD = 4 bh).
    int lin = blockIdx.y * gridDim.x + blockIdx.x;   // 0..511
    int wg  = (lin & 7) * 64 + (lin >> 3);
    int bh = wg >> 4, pair = wg & 15;
    int b = bh >> 4, h = bh & 15;

    int krow[4], kd8[4], vd[4], vkg[4];
#pragma unroll
    for (int it = 0; it < 4; it++) {
        int idx = it * 256 + tid;
        krow[it] = idx >> 4; kd8[it] = (idx & 15) * 8;
        vd[it] = idx >> 3;   vkg[it] = (idx & 7) * 8;
    }

    for (int seg = 0; seg < 2; seg++) {
        int t = seg == 0 ? (31 - pair) : pair;
        int q0 = t * 64;

        bf16x8 qf[4];
        size_t baseQ = ((size_t)(b * S_ + q0 + w * 16 + l15)) * HD_ + h * D_;
#pragma unroll
        for (int ks = 0; ks < 4; ks++)
            qf[ks] = *(const bf16x8*)(Q + baseQ + ks * 32 + quad * 8);

        f32x4 of[8];
#pragma unroll
        for (int nt = 0; nt < 8; nt++)
#pragma unroll
            for (int r = 0; r < 4; r++) of[nt][r] = 0.f;
        float mreg = -30000.f, lreg = 0.f;
        int qrow = q0 + w * 16 + l15;

        int nch = t + 1;

        // depth-2 register prefetch: A = even chunks, B = odd chunks
        bf16x8 kpA[4], vpA[4], kpB[4], vpB[4];
#pragma unroll
        for (int it = 0; it < 4; it++) {
            kpA[it] = *(const bf16x8*)(K + ((size_t)(b * S_ + krow[it])) * HD_ + h * D_ + kd8[it]);
            vpA[it] = *(const bf16x8*)(Vt + ((size_t)(bh * 128 + vd[it])) * S_ + vkg[it]);
        }
        if (nch > 1) {
#pragma unroll
            for (int it = 0; it < 4; it++) {
                kpB[it] = *(const bf16x8*)(K + ((size_t)(b * S_ + 64 + krow[it])) * HD_ + h * D_ + kd8[it]);
                vpB[it] = *(const bf16x8*)(Vt + ((size_t)(bh * 128 + vd[it])) * S_ + 64 + vkg[it]);
            }
        }

        for (int c = 0; c < nch; c++) {
            int k0 = c * 64;
            __syncthreads();
            if ((c & 1) == 0) {
#pragma unroll
                for (int it = 0; it < 4; it++) {
                    *(bf16x8*)(Ks + krow[it] * KS_ST + kd8[it]) = kpA[it];
                    *(bf16x8*)(Vs + vd[it] * VT_ST + vkg[it]) = vpA[it];
                }
            } else {
#pragma unroll
                for (int it = 0; it < 4; it++) {
                    *(bf16x8*)(Ks + krow[it] * KS_ST + kd8[it]) = kpB[it];
                    *(bf16x8*)(Vs + vd[it] * VT_ST + vkg[it]) = vpB[it];
                }
            }
            __syncthreads();
            if (c + 2 < nch) {
                int k2 = k0 + 128;
                if ((c & 1) == 0) {
#pragma unroll
                    for (int it = 0; it < 4; it++) {
                        kpA[it] = *(const bf16x8*)(K + ((size_t)(b * S_ + k2 + krow[it])) * HD_ + h * D_ + kd8[it]);
                        vpA[it] = *(const bf16x8*)(Vt + ((size_t)(bh * 128 + vd[it])) * S_ + k2 + vkg[it]);
                    }
                } else {
#pragma unroll
                    for (int it = 0; it < 4; it++) {
                        kpB[it] = *(const bf16x8*)(K + ((size_t)(b * S_ + k2 + krow[it])) * HD_ + h * D_ + kd8[it]);
                        vpB[it] = *(const bf16x8*)(Vt + ((size_t)(bh * 128 + vd[it])) * S_ + k2 + vkg[it]);
                    }
                }
            }

            f32x4 sf[4];
#pragma unroll
            for (int nt = 0; nt < 4; nt++)
#pragma unroll
                for (int r = 0; r < 4; r++) sf[nt][r] = 0.f;
#pragma unroll
            for (int ks = 0; ks < 4; ks++) {
                int koff = ks * 32 + quad * 8;
                bf16x8 qa = qf[ks];
#pragma unroll
                for (int nt = 0; nt < 4; nt++) {
                    bf16x8 kb = *(const bf16x8*)(Ks + (nt * 16 + l15) * KS_ST + koff);
                    sf[nt] = __builtin_amdgcn_mfma_f32_16x16x32_bf16(kb, qa, sf[nt], 0, 0, 0);
                }
            }

#pragma unroll
            for (int nt = 0; nt < 4; nt++) {
                int keyb = k0 + nt * 16 + quad * 4;
#pragma unroll
                for (int r = 0; r < 4; r++) {
                    float sv = sf[nt][r] * SCALE_;
                    sf[nt][r] = (keyb + r > qrow) ? -30000.f : sv;
                }
            }

            float t0 = fmaxf(fmaxf(sf[0][0], sf[0][1]), fmaxf(sf[0][2], sf[0][3]));
            float t1 = fmaxf(fmaxf(sf[1][0], sf[1][1]), fmaxf(sf[1][2], sf[1][3]));
            float t2 = fmaxf(fmaxf(sf[2][0], sf[2][1]), fmaxf(sf[2][2], sf[2][3]));
            float t3 = fmaxf(fmaxf(sf[3][0], sf[3][1]), fmaxf(sf[3][2], sf[3][3]));
            float cmax = fmaxf(fmaxf(t0, t1), fmaxf(t2, t3));
            cmax = fmaxf(cmax, __shfl_xor(cmax, 16, 64));
            cmax = fmaxf(cmax, __shfl_xor(cmax, 32, 64));
            float mnew = fmaxf(mreg, cmax);
            float a = __expf(mreg - mnew);
            mreg = mnew;
#pragma unroll
            for (int nt = 0; nt < 4; nt++)
#pragma unroll
                for (int r = 0; r < 4; r++)
                    sf[nt][r] = __expf(sf[nt][r] - mnew);
            float s0 = (sf[0][0] + sf[0][1]) + (sf[0][2] + sf[0][3]);
            float s1 = (sf[1][0] + sf[1][1]) + (sf[1][2] + sf[1][3]);
            float s2 = (sf[2][0] + sf[2][1]) + (sf[2][2] + sf[2][3]);
            float s3 = (sf[3][0] + sf[3][1]) + (sf[3][2] + sf[3][3]);
            float psum = (s0 + s1) + (s2 + s3);
            psum += __shfl_xor(psum, 16, 64);
            psum += __shfl_xor(psum, 32, 64);
            lreg = lreg * a + psum;

            float al[4];
#pragma unroll
            for (int r = 0; r < 4; r++) al[r] = __shfl(a, quad * 4 + r, 16);

#pragma unroll
            for (int nt = 0; nt < 4; nt++)
#pragma unroll
                for (int r = 0; r < 4; r++)
                    Ps[(w * 16 + l15) * VT_ST + nt * 16 + quad * 4 + r] = f2bf(sf[nt][r]);
#pragma unroll
            for (int nt = 0; nt < 8; nt++)
#pragma unroll
                for (int r = 0; r < 4; r++) of[nt][r] *= al[r];

#pragma unroll
            for (int ks2 = 0; ks2 < 2; ks2++) {
                int koff = ks2 * 32 + quad * 8;
                bf16x8 pa = *(const bf16x8*)(Ps + (w * 16 + l15) * VT_ST + koff);
#pragma unroll
                for (int nt = 0; nt < 8; nt++) {
                    bf16x8 vb = *(const bf16x8*)(Vs + (nt * 16 + l15) * VT_ST + koff);
                    of[nt] = __builtin_amdgcn_mfma_f32_16x16x32_bf16(pa, vb, of[nt], 0, 0, 0);
                }
            }
        }

        float linv = 1.f / lreg;
        float inv[4];
#pragma unroll
        for (int r = 0; r < 4; r++) inv[r] = __shfl(linv, quad * 4 + r, 16);
        int rowb = q0 + w * 16 + quad * 4;
#pragma unroll
        for (int r = 0; r < 4; r++) {
            size_t base = ((size_t)(b * S_ + rowb + r)) * HD_ + h * D_;
#pragma unroll
            for (int nt = 0; nt < 8; nt++)
                O[base + nt * 16 + l15] = f2bf(of[nt][r] * inv[r]);
        }
    }
}

// ---------------------------------------------------------------------------
extern "C" void kernel_launch(void* const* d_in, const int* in_sizes, int n_in,
                              void* d_out, int out_size, void* d_ws, size_t ws_size,
                              hipStream_t stream) {
    const void* x    = d_in[0];
    const void* mask = d_in[1];
    const void* Wq = d_in[2];  const void* bq = d_in[3];
    const void* Aq = d_in[4];  const void* Bq = d_in[5];
    const void* Wk = d_in[6];  const void* bk = d_in[7];
    const void* Ak = d_in[8];  const void* Bk = d_in[9];
    const void* Wv = d_in[10]; const void* bv = d_in[11];
    const void* Av = d_in[12]; const void* Bv = d_in[13];
    const void* Wo = d_in[14]; const void* bo = d_in[15];
    const void* Ao = d_in[16]; const void* Bo = d_in[17];

    char* ws = (char*)d_ws;
    const long MB = 1 << 20;
    int* flags = (int*)ws;
    u16* Xb    = (u16*)(ws + 1  * MB);   // 16 MB
    u16* Acat  = (u16*)(ws + 17 * MB);   // 2 MB
    u16* Bmcat = (u16*)(ws + 19 * MB);   // 2 MB
    u16* hg3   = (u16*)(ws + 21 * MB);   // 3 MB  [M,384] bf16
    u16* hgo   = (u16*)(ws + 24 * MB);   // 1 MB  [M,128] bf16
    u16* Qb    = (u16*)(ws + 25 * MB);   // 16 MB; hg3f pre-lives here; Wob after flash
    u16* Kb    = (u16*)(ws + 41 * MB);   // 16 MB; hgof after flash
    u16* Vb    = (u16*)(ws + 57 * MB);   // 16 MB; Ob after transpose
    u16* Vt    = (u16*)(ws + 73 * MB);   // 16 MB (written after Wcat dead)
    u16* Wcat  = (u16*)(ws + 73 * MB);   // 24 MB [6144][2048]; dead after QKV GEMM (end 97 MB)
    float* hg3f = (float*)Qb;            // 6 MB  [M,384] f32 (dead before QKV writes Qb)
    float* hgof = (float*)Kb;            // 2 MB  [M,128] f32 (Kb dead after flash)
    u16* Wob   = Qb;                     // Wo converted after flash (Qb dead)
    u16* Ob    = Vb;                     // Vb dead after transpose

    k_detect<<<1, 64, 0, stream>>>(x, flags);
    k_zero<<<1536, 256, 0, stream>>>((float4*)hg3f, 393216);     // 4096*384 f32
    const long NCVT = NX_ + 8 * NA1_ + 3 * NW_;   // 23068672
    k_cvt_all<<<NCVT / 1024, 256, 0, stream>>>(
        x, Aq, Ak, Av, Ao, Bq, Bk, Bv, Bo, Wq, Wk, Wv,
        Xb, Acat, Bmcat, Wcat, flags);

    // qkv LoRA-h: hg3f[m][p*128+er] via split-K x4, then cvt to bf16
    k_gemm_sk<<<dim3(3, M_ / BM_, 4), 256, 0, stream>>>(
        Xb, E_, Acat, E_, E_, mask, hg3f, 384, flags);
    k_cvtf<<<1536, 256, 0, stream>>>(hg3f, hg3, 1572864);

    // fused QKV projection: r11 pipeline, BMt=256, grid (24,16) = 384 blocks
    k_gemm8p<256><<<dim3(6144 / 256, M_ / 256), 512, 0, stream>>>(
        Xb, E_, Wcat, E_, E_, hg3, 384, Bmcat, KL_,
        bq, bk, bv, Qb, HD_, 3, flags);

    k_rope3<<<256, 256, 0, stream>>>(Qb, Kb);
    k_transpose_v<<<dim3(S_ / 32, HD_ / 32, B_), 256, 0, stream>>>(Vb, Vt);

    // flash: paired q-tiles, 512 perfectly-balanced blocks (2/CU, no tail)
    k_flash8<<<dim3(16, 32), 256, 0, stream>>>(Qb, Kb, Vt, Ob);

    // out-proj LoRA-h via split-K x4 (into dead Kb region), Wo cvt (dead Qb region)
    k_zero<<<512, 256, 0, stream>>>((float4*)hgof, 131072);      // 4096*128 f32
    k_cvt<<<NW_ / 1024, 256, 0, stream>>>(Wo, Wob, (int)NW_, flags);
    k_gemm_sk<<<dim3(1, M_ / BM_, 4), 256, 0, stream>>>(
        Ob, HD_, Acat + 3 * NA1_, E_, E_, mask, hgof, KL_, flags);
    k_cvtf<<<512, 256, 0, stream>>>(hgof, hgo, 524288);

    // output projection: r11 pipeline, BMt=128, grid (8,32) = 256 blocks
    k_gemm8p<128><<<dim3(HD_ / 256, M_ / 128), 512, 0, stream>>>(
        Ob, HD_, Wob, E_, E_, hgo, KL_, Bmcat + 3 * NA1_, KL_,
        bo, nullptr, nullptr, d_out, HD_, 2, flags);
}

// Round 10
// 648.434 us; speedup vs baseline: 1.1406x; 1.1103x over previous
//
#include <hip/hip_runtime.h>

// RStarcoderAttention: MoE-LoRA QKV proj + RoPE + causal flash attention + LoRA out proj.
// B=2 S=2048 E=2048 H=16 D=128 NE=8 R=16. fp32 accumulation everywhere.
// Round 16: flash staging rework (single lever). k_flash9: K/V staged via
// global_load_lds direct-to-LDS (issue chunk c+1 at start of chunk c, consume
// next chunk; T14 issue-early/consume-late), ONE __syncthreads per chunk (its
// builtin vmcnt(0) drain is cheap - loads had ~2000cy to land). Removes the
// reg->LDS write phase + 1 barrier/chunk + 64 prefetch VGPRs vs r15.
// Unpadded [64][128]/[128][64] tiles with BOTH-SIDES XOR swizzle (rule 21):
// per-lane pre-swizzled GLOBAL src (granule ^= row&7), linear LDS dest,
// ds_reads apply the same XOR -> 2-way banks (free). LDS 73KB -> 2 blocks/CU.
// Paired q-tiles + XCD swizzle kept from r15. GEMMs (r11 k_gemm8p, QKV 210us),
// rope3, split-K LoRA, cvt: unchanged. absmax must stay 0.3049316.

#define B_ 2
#define S_ 2048
#define E_ 2048
#define H_ 16
#define D_ 128
#define NE_ 8
#define R_ 16
#define HD_ 2048
#define M_ 4096          // B*S tokens
#define KL_ 128          // NE*R

typedef unsigned short u16;
typedef unsigned int u32;
typedef __attribute__((ext_vector_type(8))) short bf16x8;
typedef __attribute__((ext_vector_type(4))) float f32x4;

typedef const __attribute__((address_space(1))) void gvoid_t;
typedef __attribute__((address_space(3))) void svoid_t;

__device__ __forceinline__ float bf2f(u16 u) {
    union { u32 i; float f; } v; v.i = ((u32)u) << 16; return v.f;
}
__device__ __forceinline__ u16 f2bf(float f) {
    union { float f; u32 i; } v; v.f = f;
    u32 x = v.i;
    return (u16)((x + 0x7fffu + ((x >> 16) & 1u)) >> 16);   // RNE
}
__device__ __forceinline__ float ldf(const void* p, size_t i, int f) {
    return f ? ((const float*)p)[i] : bf2f(((const u16*)p)[i]);
}
__device__ __forceinline__ float4 ld4(const void* p, size_t i, int f) {
    if (f) return *(const float4*)((const float*)p + i);
    ushort4 v = *(const ushort4*)((const u16*)p + i);
    return make_float4(bf2f(v.x), bf2f(v.y), bf2f(v.z), bf2f(v.w));
}

// ---------------------------------------------------------------------------
__global__ void k_detect(const void* __restrict__ x, int* __restrict__ flags) {
    __shared__ int votes[2];
    int tid = threadIdx.x;
    if (tid < 2) votes[tid] = 0;
    __syncthreads();
    const u32* p = (const u32*)x;
    int bad = 0, tot = 0;
    for (int i = tid; i < 4096; i += 64) {
        u32 lo = p[i] & 0xffffu;
        if (lo) {
            tot++;
            int e = (int)((lo >> 7) & 0xffu);
            if (e < 100 || e > 150) bad++;
        }
    }
    atomicAdd(&votes[0], bad);
    atomicAdd(&votes[1], tot);
    __syncthreads();
    if (tid == 0) flags[0] = (votes[1] > 0 && votes[0] * 10 > votes[1] * 3) ? 1 : 0;
}

// ---------------------------------------------------------------------------
// Generic fp32/bf16 -> bf16 conversion (4 el/thread).
__global__ void k_cvt(const void* __restrict__ src, u16* __restrict__ dst, int n,
                      const int* __restrict__ flags) {
    int fin = flags[0];
    int i = (blockIdx.x * 256 + threadIdx.x) * 4;
    if (i >= n) return;
    float4 v = ld4(src, i, fin);
    ushort4 o;
    o.x = f2bf(v.x); o.y = f2bf(v.y); o.z = f2bf(v.z); o.w = f2bf(v.w);
    *(ushort4*)(dst + i) = o;
}

// f32 -> bf16 (4 el/thread), always-f32 source.
__global__ void k_cvtf(const float* __restrict__ src, u16* __restrict__ dst, int n) {
    int i = (blockIdx.x * 256 + threadIdx.x) * 4;
    if (i >= n) return;
    float4 v = *(const float4*)(src + i);
    ushort4 o;
    o.x = f2bf(v.x); o.y = f2bf(v.y); o.z = f2bf(v.z); o.w = f2bf(v.w);
    *(ushort4*)(dst + i) = o;
}

// zero f32 buffer (float4/thread)
__global__ void k_zero(float4* __restrict__ p, int n4) {
    int i = blockIdx.x * 256 + threadIdx.x;
    if (i < n4) p[i] = make_float4(0.f, 0.f, 0.f, 0.f);
}

// ---------------------------------------------------------------------------
// Batched conversion: x -> Xb; Aq..Ao -> Acat; Bq..Bo -> Bmcat; Wq/Wk/Wv -> Wcat.
#define NX_  8388608L   // M*E
#define NA1_ 262144L    // KL*E (also HD*KL)
#define NW_  4194304L   // E*HD
__global__ void k_cvt_all(
    const void* __restrict__ x,
    const void* __restrict__ Aq, const void* __restrict__ Ak,
    const void* __restrict__ Av, const void* __restrict__ Ao,
    const void* __restrict__ Bq, const void* __restrict__ Bk,
    const void* __restrict__ Bv, const void* __restrict__ Bo,
    const void* __restrict__ Wq, const void* __restrict__ Wk,
    const void* __restrict__ Wv,
    u16* __restrict__ Xb, u16* __restrict__ Acat, u16* __restrict__ Bmcat,
    u16* __restrict__ Wcat,
    const int* __restrict__ flags) {
    int fin = flags[0];
    long i = (long)(blockIdx.x * 256 + threadIdx.x) * 4;
    const void* src; u16* dst; long off;
    if (i < NX_) { src = x; dst = Xb; off = i; }
    else if (i < NX_ + 4 * NA1_) {
        long j = i - NX_; int p = (int)(j >> 18); off = j & (NA1_ - 1);
        src = (p == 0) ? Aq : (p == 1) ? Ak : (p == 2) ? Av : Ao;
        dst = Acat + (long)p * NA1_;
    } else if (i < NX_ + 8 * NA1_) {
        long j = i - NX_ - 4 * NA1_; int p = (int)(j >> 18); off = j & (NA1_ - 1);
        src = (p == 0) ? Bq : (p == 1) ? Bk : (p == 2) ? Bv : Bo;
        dst = Bmcat + (long)p * NA1_;
    } else {
        long j = i - NX_ - 8 * NA1_; int p = (int)(j / NW_); off = j - (long)p * NW_;
        src = (p == 0) ? Wq : (p == 1) ? Wk : Wv;
        dst = Wcat + (long)p * NW_;
    }
    float4 v = ld4(src, off, fin);
    ushort4 o;
    o.x = f2bf(v.x); o.y = f2bf(v.y); o.z = f2bf(v.z); o.w = f2bf(v.w);
    *(ushort4*)(dst + off) = o;
}

// ---------------------------------------------------------------------------
// Split-K GEMM for the small LoRA projections: Cf[m][n] += mask * sum_k A*B.
#define BM_ 128
#define BN_ 128
#define BK_ 64

__global__ __launch_bounds__(256, 2) void k_gemm_sk(
    const u16* __restrict__ A, int lda,
    const u16* __restrict__ Bw, int ldb, int K,
    const void* __restrict__ mask,
    float* __restrict__ Cf, int ldc,
    const int* __restrict__ flags) {
    __shared__ __align__(16) u16 As[BM_ * BK_];   // 16 KB
    __shared__ __align__(16) u16 Bs[BN_ * BK_];   // 16 KB
    int fin = flags[0];
    int tid = threadIdx.x;
    int w = tid >> 6, lane = tid & 63;
    int l15 = lane & 15, quad = lane >> 4;
    int wm = w >> 1, wn = w & 1;
    int m0 = blockIdx.y * BM_, n0 = blockIdx.x * BN_;
    int lrow = lane >> 3;          // 0..7
    int lcol = (lane & 7) * 8;     // 16B granule

    f32x4 acc[4][4];
#pragma unroll
    for (int mt = 0; mt < 4; mt++)
#pragma unroll
        for (int nt = 0; nt < 4; nt++)
#pragma unroll
            for (int r = 0; r < 4; r++) acc[mt][nt][r] = 0.f;

    int iters = (K / BK_) / gridDim.z;
    int it0 = blockIdx.z * iters;
    for (int it = it0; it < it0 + iters; it++) {
        int kb = it * BK_;
        __syncthreads();
#pragma unroll
        for (int i = 0; i < 4; i++) {
            int rowb = (w * 4 + i) * 8;
            int r = rowb + lrow;
            __builtin_amdgcn_global_load_lds(
                (gvoid_t*)(A + (size_t)(m0 + r) * lda + kb + lcol),
                (svoid_t*)(As + rowb * BK_), 16, 0, 0);
            __builtin_amdgcn_global_load_lds(
                (gvoid_t*)(Bw + (size_t)(n0 + r) * ldb + kb + lcol),
                (svoid_t*)(Bs + rowb * BK_), 16, 0, 0);
        }
        __syncthreads();
#pragma unroll
        for (int kk = 0; kk < 2; kk++) {
            int ko = kk * 32 + quad * 8;
            bf16x8 af[4], bf[4];
#pragma unroll
            for (int mt = 0; mt < 4; mt++)
                af[mt] = *(const bf16x8*)(As + (wm * 64 + mt * 16 + l15) * BK_ + ko);
#pragma unroll
            for (int nt = 0; nt < 4; nt++)
                bf[nt] = *(const bf16x8*)(Bs + (wn * 64 + nt * 16 + l15) * BK_ + ko);
#pragma unroll
            for (int mt = 0; mt < 4; mt++)
#pragma unroll
                for (int nt = 0; nt < 4; nt++)
                    acc[mt][nt] = __builtin_amdgcn_mfma_f32_16x16x32_bf16(
                        af[mt], bf[nt], acc[mt][nt], 0, 0, 0);
        }
    }

#pragma unroll
    for (int mt = 0; mt < 4; mt++) {
#pragma unroll
        for (int r = 0; r < 4; r++) {
            int m = m0 + wm * 64 + mt * 16 + quad * 4 + r;
#pragma unroll
            for (int nt = 0; nt < 4; nt++) {
                int n = n0 + wn * 64 + nt * 16 + l15;
                float v = acc[mt][nt][r] * ldf(mask, (size_t)m * NE_ + ((n & 127) >> 4), fin);
                atomicAdd(&Cf[(size_t)m * ldc + n], v);
            }
        }
    }
}

// ---------------------------------------------------------------------------
// Big GEMM (r11, best measured). Tile BMt x 256, BK=32, 8 waves (2m x 4n), 4 LDS
// buffers, 3-tile-deep prefetch, counted vmcnt once per K-tile. LDS subtiles
// fragment-native (16 rows x 32 k, lane-linear -> conflict-free ds_read_b128).
// store_mode 2: C f32/bf16 by fin; store_mode 3: fused QKV (p = n0>>11 selects
// bias / lora segment / output third).
template <int BMt>
__global__ __launch_bounds__(512, 2) void k_gemm8p(
    const u16* __restrict__ A, int lda,
    const u16* __restrict__ Bw, int ldb, int K1,
    const u16* __restrict__ A2, int lda2,
    const u16* __restrict__ B2, int K2,
    const void* __restrict__ bias0, const void* __restrict__ bias1,
    const void* __restrict__ bias2,
    void* __restrict__ C, int ldc, int store_mode,
    const int* __restrict__ flags) {
    constexpr int MT  = BMt / 32;    // m-frags per wave
    constexpr int NSA = BMt / 16;    // A subtiles per K-tile
    constexpr int LA  = BMt / 128;   // A stage loads per wave per tile
    constexpr int L   = LA + 2;      // total stage loads per wave per tile
    __shared__ __align__(16) u16 As[4][NSA * 512];   // 4 x (BMt*32) el
    __shared__ __align__(16) u16 Bs[4][16 * 512];    // 4 x 16 KB
    int fin = flags[0];
    int tid = threadIdx.x;
    int w = tid >> 6, lane = tid & 63;
    int l15 = lane & 15, quad = lane >> 4;
    int wm = w >> 2, wn = w & 3;             // 2 x 4 wave grid

    // XCD-aware swizzle (grid sizes are multiples of 8)
    int lin = blockIdx.y * gridDim.x + blockIdx.x;
    int cpx = (gridDim.x * gridDim.y) >> 3;
    int wg = (lin & 7) * cpx + (lin >> 3);
    int m0 = (wg / gridDim.x) * BMt;
    int n0 = (wg % gridDim.x) * 256;

    int p = (store_mode == 3) ? (n0 >> 11) : 0;
    const u16* A2p = A2 + p * 128;
    const u16* B2p = B2 + (long)p * NA1_;
    int nloc = (store_mode == 3) ? (n0 & 2047) : n0;

    int nk1 = K1 >> 5;
    int NT = nk1 + (K2 >> 5);

    f32x4 acc[MT][4];
#pragma unroll
    for (int mt = 0; mt < MT; mt++)
#pragma unroll
        for (int nt = 0; nt < 4; nt++)
#pragma unroll
            for (int r = 0; r < 4; r++) acc[mt][nt][r] = 0.f;

    auto stageA = [&](int kt) {
        const u16* pa; size_t sa; int kb;
        if (kt < nk1) { pa = A;   sa = (size_t)lda;  kb = kt * 32; }
        else          { pa = A2p; sa = (size_t)lda2; kb = (kt - nk1) * 32; }
        int buf = kt & 3;
#pragma unroll
        for (int j = 0; j < LA; j++) {
            int rb = w * LA + j;
            __builtin_amdgcn_global_load_lds(
                (gvoid_t*)(pa + (size_t)(m0 + rb * 16 + l15) * sa + kb + quad * 8),
                (svoid_t*)(&As[buf][rb * 512]), 16, 0, 0);
        }
    };
    auto stageB = [&](int kt) {
        const u16* pb; size_t sb; int kb, nb;
        if (kt < nk1) { pb = Bw;  sb = (size_t)ldb; kb = kt * 32;          nb = n0; }
        else          { pb = B2p; sb = (size_t)K2;  kb = (kt - nk1) * 32;  nb = nloc; }
        int buf = kt & 3;
#pragma unroll
        for (int j = 0; j < 2; j++) {
            int rb = w * 2 + j;
            __builtin_amdgcn_global_load_lds(
                (gvoid_t*)(pb + (size_t)(nb + rb * 16 + l15) * sb + kb + quad * 8),
                (svoid_t*)(&Bs[buf][rb * 512]), 16, 0, 0);
        }
    };

    // prologue: tiles 0,1,2 fully staged (3L loads in flight), wait tile 0
    stageA(0); stageB(0);
    stageA(1); stageB(1);
    stageA(2); stageB(2);
    if constexpr (L == 4) asm volatile("s_waitcnt vmcnt(8)" ::: "memory");
    else                  asm volatile("s_waitcnt vmcnt(6)" ::: "memory");
    __builtin_amdgcn_s_barrier();

    for (int kt = 0; kt < NT; kt++) {
        int buf = kt & 3;
        bool pre = (kt + 3 < NT);

        // ---- phase 0: read af (held through both phases) + bf01; stage A(kt+3)
        bf16x8 af[MT], bfr[4];
#pragma unroll
        for (int mt = 0; mt < MT; mt++)
            af[mt] = *(const bf16x8*)(&As[buf][(wm * MT + mt) * 512 + lane * 8]);
        bfr[0] = *(const bf16x8*)(&Bs[buf][(wn * 4 + 0) * 512 + lane * 8]);
        bfr[1] = *(const bf16x8*)(&Bs[buf][(wn * 4 + 1) * 512 + lane * 8]);
        if (pre) stageA(kt + 3);
        __builtin_amdgcn_s_barrier();
        asm volatile("s_waitcnt lgkmcnt(0)" ::: "memory");
        __builtin_amdgcn_sched_barrier(0);
        __builtin_amdgcn_s_setprio(1);
#pragma unroll
        for (int mt = 0; mt < MT; mt++) {
            acc[mt][0] = __builtin_amdgcn_mfma_f32_16x16x32_bf16(af[mt], bfr[0], acc[mt][0], 0, 0, 0);
            acc[mt][1] = __builtin_amdgcn_mfma_f32_16x16x32_bf16(af[mt], bfr[1], acc[mt][1], 0, 0, 0);
        }
        __builtin_amdgcn_s_setprio(0);
        __builtin_amdgcn_s_barrier();

        // ---- phase 1: read bf23; stage B(kt+3); counted vmcnt; tile barrier
        bfr[2] = *(const bf16x8*)(&Bs[buf][(wn * 4 + 2) * 512 + lane * 8]);
        bfr[3] = *(const bf16x8*)(&Bs[buf][(wn * 4 + 3) * 512 + lane * 8]);
        if (pre) stageB(kt + 3);
        __builtin_amdgcn_s_barrier();
        asm volatile("s_waitcnt lgkmcnt(0)" ::: "memory");
        __builtin_amdgcn_sched_barrier(0);
        __builtin_amdgcn_s_setprio(1);
#pragma unroll
        for (int mt = 0; mt < MT; mt++) {
            acc[mt][2] = __builtin_amdgcn_mfma_f32_16x16x32_bf16(af[mt], bfr[2], acc[mt][2], 0, 0, 0);
            acc[mt][3] = __builtin_amdgcn_mfma_f32_16x16x32_bf16(af[mt], bfr[3], acc[mt][3], 0, 0, 0);
        }
        __builtin_amdgcn_s_setprio(0);
        // ensure tile kt+1 landed before anyone reads it (never drain to 0 mid-loop)
        if (kt + 4 <= NT) {
            if constexpr (L == 4) asm volatile("s_waitcnt vmcnt(8)" ::: "memory");
            else                  asm volatile("s_waitcnt vmcnt(6)" ::: "memory");
        } else if (kt + 3 == NT) {
            if constexpr (L == 4) asm volatile("s_waitcnt vmcnt(4)" ::: "memory");
            else                  asm volatile("s_waitcnt vmcnt(3)" ::: "memory");
        } else if (kt + 2 == NT) {
            asm volatile("s_waitcnt vmcnt(0)" ::: "memory");
        }
        __builtin_amdgcn_s_barrier();
    }

    const void* bp = (store_mode == 3) ? (p == 0 ? bias0 : p == 1 ? bias1 : bias2)
                                       : bias0;
#pragma unroll
    for (int mt = 0; mt < MT; mt++) {
#pragma unroll
        for (int r = 0; r < 4; r++) {
            int m = m0 + wm * (BMt / 2) + mt * 16 + quad * 4 + r;
#pragma unroll
            for (int nt = 0; nt < 4; nt++) {
                int n = n0 + wn * 64 + nt * 16 + l15;
                float v = acc[mt][nt][r];
                if (bp) v += ldf(bp, (size_t)(n & 2047), fin);
                if (store_mode == 3) {
                    ((u16*)C)[(size_t)p * 8388608 + (size_t)m * 2048 + (n & 2047)] = f2bf(v);
                } else {
                    if (fin) ((float*)C)[(size_t)m * ldc + n] = v;
                    else     ((u16*)C)[(size_t)m * ldc + n] = f2bf(v);
                }
            }
        }
    }
}

// ---------------------------------------------------------------------------
// RoPE: one thread owns (b,s, 4 consecutive d2) and applies to all 16 heads of
// Q and K. 64x fewer transcendentals than per-element; ushort4 loads/stores.
__global__ void k_rope3(u16* __restrict__ Q, u16* __restrict__ K) {
    int idx = blockIdx.x * 256 + threadIdx.x;    // 65536 threads
    int d2g = idx & 15;                          // 4-wide d2 group
    int rs  = idx >> 4;                          // b*S + s  (0..4095)
    int s   = rs & (S_ - 1);
    float cs[4], sn[4];
#pragma unroll
    for (int j = 0; j < 4; j++) {
        int d2 = d2g * 4 + j;
        float inv = powf(10000.f, -(float)d2 * (1.f / 64.f));
        float fr = (float)s * inv;
        sincosf(fr, &sn[j], &cs[j]);
    }
#pragma unroll
    for (int h = 0; h < H_; h++) {
        size_t base = ((size_t)(rs * H_ + h)) << 7;
#pragma unroll
        for (int a = 0; a < 2; a++) {
            u16* Y = a ? K : Q;
            ushort4 lo = *(const ushort4*)(Y + base + d2g * 4);
            ushort4 hi = *(const ushort4*)(Y + base + 64 + d2g * 4);
            ushort4 lo2, hi2;
            {
                float t0 = bf2f(lo.x), t1 = bf2f(hi.x);
                lo2.x = f2bf(t0 * cs[0] - t1 * sn[0]); hi2.x = f2bf(t1 * cs[0] + t0 * sn[0]);
            }
            {
                float t0 = bf2f(lo.y), t1 = bf2f(hi.y);
                lo2.y = f2bf(t0 * cs[1] - t1 * sn[1]); hi2.y = f2bf(t1 * cs[1] + t0 * sn[1]);
            }
            {
                float t0 = bf2f(lo.z), t1 = bf2f(hi.z);
                lo2.z = f2bf(t0 * cs[2] - t1 * sn[2]); hi2.z = f2bf(t1 * cs[2] + t0 * sn[2]);
            }
            {
                float t0 = bf2f(lo.w), t1 = bf2f(hi.w);
                lo2.w = f2bf(t0 * cs[3] - t1 * sn[3]); hi2.w = f2bf(t1 * cs[3] + t0 * sn[3]);
            }
            *(ushort4*)(Y + base + d2g * 4) = lo2;
            *(ushort4*)(Y + base + 64 + d2g * 4) = hi2;
        }
    }
}

// ---------------------------------------------------------------------------
// Vb [B,S,H*D] -> Vt [B*H*D, S]
__global__ void k_transpose_v(const u16* __restrict__ Vb, u16* __restrict__ Vt) {
    __shared__ u16 t[32][33];
    int s0 = blockIdx.x * 32;
    int n0 = blockIdx.y * 32;
    int b  = blockIdx.z;
    int tx = threadIdx.x & 31, ty = threadIdx.x >> 5;
#pragma unroll
    for (int r = 0; r < 4; r++)
        t[ty + r * 8][tx] = Vb[((size_t)(b * S_ + s0 + ty + r * 8)) * HD_ + n0 + tx];
    __syncthreads();
#pragma unroll
    for (int r = 0; r < 4; r++)
        Vt[((size_t)(b * HD_ + n0 + ty + r * 8)) * S_ + s0 + tx] = t[tx][ty + r * 8];
}

// ---------------------------------------------------------------------------
// MFMA flash attention, paired q-tiles, global_load_lds staging.
// Grid (16,32) = 512 blocks (2/CU), each block does q-tiles (31-pair, pair) =
// exactly 33 chunks. Per chunk: issue 8 gload_lds for chunk c+1 into buf^1,
// compute QK/softmax/PV from buf, ONE __syncthreads (drains loads - they had
// the whole chunk to land). K tile [64][128] and V^T tile [128][64] unpadded,
// both-sides XOR swizzle: global src granule ^= row&7, ds_read same XOR.
#define VT_ST 72
#define SCALE_ 0.088388347648318447f

__global__ __launch_bounds__(256, 2) void k_flash9(
    const u16* __restrict__ Q, const u16* __restrict__ K,
    const u16* __restrict__ Vt, u16* __restrict__ O) {
    __shared__ __align__(16) u16 Ks[2][64 * 128];   // 2 x 16 KB, swizzled
    __shared__ __align__(16) u16 Vs[2][128 * 64];   // 2 x 16 KB, swizzled
    __shared__ __align__(16) u16 Ps[64 * VT_ST];    // 9216 B (padded, unchanged)
    int tid = threadIdx.x;
    int w = tid >> 6, lane = tid & 63;
    int l15 = lane & 15, quad = lane >> 4;
    int swz = l15 & 7;                       // row&7 for all my fragment rows

    // 512 blocks; XCD-contiguous (64 wg per XCD = 4 bh).
    int lin = blockIdx.y * gridDim.x + blockIdx.x;   // 0..511
    int wg  = (lin & 7) * 64 + (lin >> 3);
    int bh = wg >> 4, pair = wg & 15;
    int b = bh >> 4, h = bh & 15;

    // stage chunk c (64 keys) into buf: 4 K-loads + 4 V-loads per thread.
    // K: granule lin16 = (w*4+j)*64 + lane; row = lin16>>4 (0..63), gsw = lin16&15;
    //    src col granule = gsw ^ (row&7). V: lin8 rows of 8 granules.
    auto stageKV = [&](int c, int buf) {
        int k0s = c * 64;
#pragma unroll
        for (int j = 0; j < 4; j++) {
            int g = (w * 4 + j) * 64 + lane;
            int row = g >> 4;
            int gs = (g & 15) ^ (row & 7);
            __builtin_amdgcn_global_load_lds(
                (gvoid_t*)(K + (size_t)(b * S_ + k0s + row) * HD_ + h * D_ + gs * 8),
                (svoid_t*)(&Ks[buf][(w * 4 + j) * 512]), 16, 0, 0);
        }
#pragma unroll
        for (int j = 0; j < 4; j++) {
            int g = (w * 4 + j) * 64 + lane;
            int row = g >> 3;
            int gs = (g & 7) ^ (row & 7);
            __builtin_amdgcn_global_load_lds(
                (gvoid_t*)(Vt + (size_t)(bh * 128 + row) * S_ + k0s + gs * 8),
                (svoid_t*)(&Vs[buf][(w * 4 + j) * 512]), 16, 0, 0);
        }
    };

    for (int seg = 0; seg < 2; seg++) {
        int t = seg == 0 ? (31 - pair) : pair;
        int q0 = t * 64;

        bf16x8 qf[4];
        size_t baseQ = ((size_t)(b * S_ + q0 + w * 16 + l15)) * HD_ + h * D_;
#pragma unroll
        for (int ks = 0; ks < 4; ks++)
            qf[ks] = *(const bf16x8*)(Q + baseQ + ks * 32 + quad * 8);

        f32x4 of[8];
#pragma unroll
        for (int nt = 0; nt < 8; nt++)
#pragma unroll
            for (int r = 0; r < 4; r++) of[nt][r] = 0.f;
        float mreg = -30000.f, lreg = 0.f;
        int qrow = q0 + w * 16 + l15;

        int nch = t + 1;

        stageKV(0, 0);
        __syncthreads();

        for (int c = 0; c < nch; c++) {
            int k0 = c * 64;
            int buf = c & 1;
            if (c + 1 < nch) stageKV(c + 1, buf ^ 1);
            const u16* Ksb = Ks[buf];
            const u16* Vsb = Vs[buf];

            // ---- swapped QK^T: S^T(64key x 16query) per wave, swizzled reads
            f32x4 sf[4];
#pragma unroll
            for (int nt = 0; nt < 4; nt++)
#pragma unroll
                for (int r = 0; r < 4; r++) sf[nt][r] = 0.f;
#pragma unroll
            for (int ks = 0; ks < 4; ks++) {
                bf16x8 qa = qf[ks];
#pragma unroll
                for (int nt = 0; nt < 4; nt++) {
                    bf16x8 kb = *(const bf16x8*)(Ksb + (nt * 16 + l15) * 128
                                                 + (((ks * 4 + quad) ^ swz) * 8));
                    sf[nt] = __builtin_amdgcn_mfma_f32_16x16x32_bf16(kb, qa, sf[nt], 0, 0, 0);
                }
            }

#pragma unroll
            for (int nt = 0; nt < 4; nt++) {
                int keyb = k0 + nt * 16 + quad * 4;
#pragma unroll
                for (int r = 0; r < 4; r++) {
                    float sv = sf[nt][r] * SCALE_;
                    sf[nt][r] = (keyb + r > qrow) ? -30000.f : sv;
                }
            }

            float t0 = fmaxf(fmaxf(sf[0][0], sf[0][1]), fmaxf(sf[0][2], sf[0][3]));
            float t1 = fmaxf(fmaxf(sf[1][0], sf[1][1]), fmaxf(sf[1][2], sf[1][3]));
            float t2 = fmaxf(fmaxf(sf[2][0], sf[2][1]), fmaxf(sf[2][2], sf[2][3]));
            float t3 = fmaxf(fmaxf(sf[3][0], sf[3][1]), fmaxf(sf[3][2], sf[3][3]));
            float cmax = fmaxf(fmaxf(t0, t1), fmaxf(t2, t3));
            cmax = fmaxf(cmax, __shfl_xor(cmax, 16, 64));
            cmax = fmaxf(cmax, __shfl_xor(cmax, 32, 64));
            float mnew = fmaxf(mreg, cmax);
            float a = __expf(mreg - mnew);
            mreg = mnew;
#pragma unroll
            for (int nt = 0; nt < 4; nt++)
#pragma unroll
                for (int r = 0; r < 4; r++)
                    sf[nt][r] = __expf(sf[nt][r] - mnew);
            float s0 = (sf[0][0] + sf[0][1]) + (sf[0][2] + sf[0][3]);
            float s1 = (sf[1][0] + sf[1][1]) + (sf[1][2] + sf[1][3]);
            float s2 = (sf[2][0] + sf[2][1]) + (sf[2][2] + sf[2][3]);
            float s3 = (sf[3][0] + sf[3][1]) + (sf[3][2] + sf[3][3]);
            float psum = (s0 + s1) + (s2 + s3);
            psum += __shfl_xor(psum, 16, 64);
            psum += __shfl_xor(psum, 32, 64);
            lreg = lreg * a + psum;

            float al[4];
#pragma unroll
            for (int r = 0; r < 4; r++) al[r] = __shfl(a, quad * 4 + r, 16);

            // P^T regs -> Ps in [query][key] layout (per-wave rows, no barrier)
#pragma unroll
            for (int nt = 0; nt < 4; nt++)
#pragma unroll
                for (int r = 0; r < 4; r++)
                    Ps[(w * 16 + l15) * VT_ST + nt * 16 + quad * 4 + r] = f2bf(sf[nt][r]);
#pragma unroll
            for (int nt = 0; nt < 8; nt++)
#pragma unroll
                for (int r = 0; r < 4; r++) of[nt][r] *= al[r];

            // ---- PV: O(16x128) += P(16x64) . V(64x128), swizzled V reads
#pragma unroll
            for (int ks2 = 0; ks2 < 2; ks2++) {
                int koff = ks2 * 32 + quad * 8;
                bf16x8 pa = *(const bf16x8*)(Ps + (w * 16 + l15) * VT_ST + koff);
#pragma unroll
                for (int nt = 0; nt < 8; nt++) {
                    bf16x8 vb = *(const bf16x8*)(Vsb + (nt * 16 + l15) * 64
                                                 + (((ks2 * 4 + quad) ^ swz) * 8));
                    of[nt] = __builtin_amdgcn_mfma_f32_16x16x32_bf16(pa, vb, of[nt], 0, 0, 0);
                }
            }

            __syncthreads();   // drains this wave's gload_lds (issued early) + rendezvous
        }

        float linv = 1.f / lreg;
        float inv[4];
#pragma unroll
        for (int r = 0; r < 4; r++) inv[r] = __shfl(linv, quad * 4 + r, 16);
        int rowb = q0 + w * 16 + quad * 4;
#pragma unroll
        for (int r = 0; r < 4; r++) {
            size_t base = ((size_t)(b * S_ + rowb + r)) * HD_ + h * D_;
#pragma unroll
            for (int nt = 0; nt < 8; nt++)
                O[base + nt * 16 + l15] = f2bf(of[nt][r] * inv[r]);
        }
    }
}

// ---------------------------------------------------------------------------
extern "C" void kernel_launch(void* const* d_in, const int* in_sizes, int n_in,
                              void* d_out, int out_size, void* d_ws, size_t ws_size,
                              hipStream_t stream) {
    const void* x    = d_in[0];
    const void* mask = d_in[1];
    const void* Wq = d_in[2];  const void* bq = d_in[3];
    const void* Aq = d_in[4];  const void* Bq = d_in[5];
    const void* Wk = d_in[6];  const void* bk = d_in[7];
    const void* Ak = d_in[8];  const void* Bk = d_in[9];
    const void* Wv = d_in[10]; const void* bv = d_in[11];
    const void* Av = d_in[12]; const void* Bv = d_in[13];
    const void* Wo = d_in[14]; const void* bo = d_in[15];
    const void* Ao = d_in[16]; const void* Bo = d_in[17];

    char* ws = (char*)d_ws;
    const long MB = 1 << 20;
    int* flags = (int*)ws;
    u16* Xb    = (u16*)(ws + 1  * MB);   // 16 MB
    u16* Acat  = (u16*)(ws + 17 * MB);   // 2 MB
    u16* Bmcat = (u16*)(ws + 19 * MB);   // 2 MB
    u16* hg3   = (u16*)(ws + 21 * MB);   // 3 MB  [M,384] bf16
    u16* hgo   = (u16*)(ws + 24 * MB);   // 1 MB  [M,128] bf16
    u16* Qb    = (u16*)(ws + 25 * MB);   // 16 MB; hg3f pre-lives here; Wob after flash
    u16* Kb    = (u16*)(ws + 41 * MB);   // 16 MB; hgof after flash
    u16* Vb    = (u16*)(ws + 57 * MB);   // 16 MB; Ob after transpose
    u16* Vt    = (u16*)(ws + 73 * MB);   // 16 MB (written after Wcat dead)
    u16* Wcat  = (u16*)(ws + 73 * MB);   // 24 MB [6144][2048]; dead after QKV GEMM (end 97 MB)
    float* hg3f = (float*)Qb;            // 6 MB  [M,384] f32 (dead before QKV writes Qb)
    float* hgof = (float*)Kb;            // 2 MB  [M,128] f32 (Kb dead after flash)
    u16* Wob   = Qb;                     // Wo converted after flash (Qb dead)
    u16* Ob    = Vb;                     // Vb dead after transpose

    k_detect<<<1, 64, 0, stream>>>(x, flags);
    k_zero<<<1536, 256, 0, stream>>>((float4*)hg3f, 393216);     // 4096*384 f32
    const long NCVT = NX_ + 8 * NA1_ + 3 * NW_;   // 23068672
    k_cvt_all<<<NCVT / 1024, 256, 0, stream>>>(
        x, Aq, Ak, Av, Ao, Bq, Bk, Bv, Bo, Wq, Wk, Wv,
        Xb, Acat, Bmcat, Wcat, flags);

    // qkv LoRA-h: hg3f[m][p*128+er] via split-K x4, then cvt to bf16
    k_gemm_sk<<<dim3(3, M_ / BM_, 4), 256, 0, stream>>>(
        Xb, E_, Acat, E_, E_, mask, hg3f, 384, flags);
    k_cvtf<<<1536, 256, 0, stream>>>(hg3f, hg3, 1572864);

    // fused QKV projection: r11 pipeline, BMt=256, grid (24,16) = 384 blocks
    k_gemm8p<256><<<dim3(6144 / 256, M_ / 256), 512, 0, stream>>>(
        Xb, E_, Wcat, E_, E_, hg3, 384, Bmcat, KL_,
        bq, bk, bv, Qb, HD_, 3, flags);

    k_rope3<<<256, 256, 0, stream>>>(Qb, Kb);
    k_transpose_v<<<dim3(S_ / 32, HD_ / 32, B_), 256, 0, stream>>>(Vb, Vt);

    // flash: paired q-tiles, gload_lds staging, 1 barrier/chunk
    k_flash9<<<dim3(16, 32), 256, 0, stream>>>(Qb, Kb, Vt, Ob);

    // out-proj LoRA-h via split-K x4 (into dead Kb region), Wo cvt (dead Qb region)
    k_zero<<<512, 256, 0, stream>>>((float4*)hgof, 131072);      // 4096*128 f32
    k_cvt<<<NW_ / 1024, 256, 0, stream>>>(Wo, Wob, (int)NW_, flags);
    k_gemm_sk<<<dim3(1, M_ / BM_, 4), 256, 0, stream>>>(
        Ob, HD_, Acat + 3 * NA1_, E_, E_, mask, hgof, KL_, flags);
    k_cvtf<<<512, 256, 0, stream>>>(hgof, hgo, 524288);

    // output projection: r11 pipeline, BMt=128, grid (8,32) = 256 blocks
    k_gemm8p<128><<<dim3(HD_ / 256, M_ / 128), 512, 0, stream>>>(
        Ob, HD_, Wob, E_, E_, hgo, KL_, Bmcat + 3 * NA1_, KL_,
        bo, nullptr, nullptr, d_out, HD_, 2, flags);
}